// Round 4
// baseline (929.438 us; speedup 1.0000x reference)
//
#include <hip/hip_runtime.h>
#include <hip/hip_bf16.h>
#include <math.h>

#define NEG_SLOPE 0.2f
#define N_LAYERS 4

typedef __bf16 bf16_t;
typedef __attribute__((ext_vector_type(8))) __bf16 bf16x8;
typedef __attribute__((ext_vector_type(4))) __bf16 bf16x4;
typedef __attribute__((ext_vector_type(4))) float f32x4;
typedef __attribute__((ext_vector_type(8))) float f32x8;

static __device__ __forceinline__ float leaky(float v){ return v > 0.f ? v : NEG_SLOPE * v; }

// ---------------- CSR build (edge structure fixed across layers) ----------------

__global__ void fill_int_kernel(int* __restrict__ p, int v, int n){
  int i = blockIdx.x*blockDim.x + threadIdx.x;
  if(i < n) p[i] = v;
}

__global__ void fill_bias_kernel(float* __restrict__ out, const float* __restrict__ b, int rows){
  int i = blockIdx.x*blockDim.x + threadIdx.x;
  if(i < rows * 128) out[i] = b[i & 127];
}

__global__ void hist_kernel(const int* __restrict__ dst, int E, int* __restrict__ deg){
  int e = blockIdx.x*blockDim.x + threadIdx.x;
  if(e < E) atomicAdd(&deg[dst[e]], 1);
}

// exclusive scan via wave shuffles: offs[0]=0, offs[i+1]=sum(deg[0..i]). One block, 256 thr.
__global__ void scan_kernel(const int* __restrict__ deg, int* __restrict__ offs, int N){
  __shared__ int wsum[4];
  int t = threadIdx.x, lane = t & 63, w = t >> 6;
  int carry = 0;
  for(int base = 0; base < N; base += 256){
    int v = (base + t < N) ? deg[base + t] : 0;
    int s = v;
#pragma unroll
    for(int o = 1; o < 64; o <<= 1){
      int u = __shfl_up(s, o);
      if(lane >= o) s += u;
    }
    if(lane == 63) wsum[w] = s;
    __syncthreads();
    int woff = 0;
    for(int i = 0; i < w; ++i) woff += wsum[i];
    if(base + t < N) offs[base + t + 1] = carry + woff + s;
    int tot = wsum[0] + wsum[1] + wsum[2] + wsum[3];
    __syncthreads();
    carry += tot;
  }
  if(t == 0) offs[0] = 0;
}

__global__ void scatter_kernel(const int* __restrict__ dst, int E,
                               const int* __restrict__ offs, int* __restrict__ cursor,
                               int* __restrict__ eids){
  int e = blockIdx.x*blockDim.x + threadIdx.x;
  if(e < E){
    int d = dst[e];
    int pos = offs[d] + atomicAdd(&cursor[d], 1);
    eids[pos] = e;
  }
}

// ---------------- weight transpose + bf16 hi/lo split ----------------

__global__ void transpose_split_kernel(const float* __restrict__ W,
                                       bf16_t* __restrict__ Th, bf16_t* __restrict__ Tl,
                                       int K, int N){
  __shared__ float t[32][33];
  int k0 = blockIdx.x * 32, n0 = blockIdx.y * 32;
  int tx = threadIdx.x, ty = threadIdx.y;
#pragma unroll
  for(int i = 0; i < 4; ++i)
    t[ty*4 + i][tx] = W[(size_t)(k0 + ty*4 + i) * N + n0 + tx];
  __syncthreads();
#pragma unroll
  for(int i = 0; i < 4; ++i){
    int n = ty*4 + i;
    float v = t[tx][n];
    bf16_t h = (bf16_t)v;
    bf16_t l = (bf16_t)(v - (float)h);
    Th[(size_t)(n0 + n) * K + k0 + tx] = h;
    Tl[(size_t)(n0 + n) * K + k0 + tx] = l;
  }
}

// ---------------- MFMA split-bf16 GEMM (single output) ----------------
// C[M][N] = A[M][K] (fp32, opt. relu) @ Bt^T, Bt hi/lo [N][K] bf16.
// SPLITK: blockIdx.z selects 128-wide K slice; atomicAdd epilogue (C pre-filled w/ bias).

template<bool RELU_A, bool HAS_BIAS, bool WRITE_BF16, bool SPLITK>
__global__ __launch_bounds__(256) void gemm_mfma_kernel(
    const float* __restrict__ A,
    const bf16_t* __restrict__ Bt_hi, const bf16_t* __restrict__ Bt_lo,
    const float* __restrict__ bias, float* __restrict__ C, bf16_t* __restrict__ Cb,
    int M, int N, int K){
  constexpr int LDK = 40;
  __shared__ bf16_t Ah[128 * LDK];
  __shared__ bf16_t Al[128 * LDK];
  __shared__ bf16_t Bh[128 * LDK];
  __shared__ bf16_t Bl[128 * LDK];

  const int tid  = threadIdx.x;
  const int lane = tid & 63;
  const int wid  = tid >> 6;
  const int wm = wid >> 1, wn = wid & 1;
  const int row0 = blockIdx.y * 128, col0 = blockIdx.x * 128;
  const int l15 = lane & 15;
  const int kb  = (lane >> 4) * 8;

  f32x4 acc[4][4];
#pragma unroll
  for(int m = 0; m < 4; ++m)
#pragma unroll
    for(int n = 0; n < 4; ++n) acc[m][n] = (f32x4){0.f, 0.f, 0.f, 0.f};

  int kbeg = 0, kend = K;
  if(SPLITK){ kbeg = blockIdx.z * 128; kend = kbeg + 128; }

  for(int k0 = kbeg; k0 < kend; k0 += 32){
    __syncthreads();
#pragma unroll
    for(int i = 0; i < 4; ++i){
      int f = tid + i * 256;
      int r = f >> 3, kq = f & 7;
      float4 v = make_float4(0.f, 0.f, 0.f, 0.f);
      if(row0 + r < M) v = *(const float4*)(A + (size_t)(row0 + r) * K + k0 + kq * 4);
      if(RELU_A){ v.x = fmaxf(v.x, 0.f); v.y = fmaxf(v.y, 0.f); v.z = fmaxf(v.z, 0.f); v.w = fmaxf(v.w, 0.f); }
      bf16_t h0 = (bf16_t)v.x, h1 = (bf16_t)v.y, h2 = (bf16_t)v.z, h3 = (bf16_t)v.w;
      bf16x4 hv = (bf16x4){h0, h1, h2, h3};
      bf16x4 lv = (bf16x4){(bf16_t)(v.x - (float)h0), (bf16_t)(v.y - (float)h1),
                           (bf16_t)(v.z - (float)h2), (bf16_t)(v.w - (float)h3)};
      *(bf16x4*)&Ah[r * LDK + kq * 4] = hv;
      *(bf16x4*)&Al[r * LDK + kq * 4] = lv;
    }
#pragma unroll
    for(int i = 0; i < 2; ++i){
      int f = tid + i * 256;
      int n = f >> 2, kq = f & 3;
      *(bf16x8*)&Bh[n * LDK + kq * 8] = *(const bf16x8*)(Bt_hi + (size_t)(col0 + n) * K + k0 + kq * 8);
      *(bf16x8*)&Bl[n * LDK + kq * 8] = *(const bf16x8*)(Bt_lo + (size_t)(col0 + n) * K + k0 + kq * 8);
    }
    __syncthreads();

    bf16x8 ah[4], al[4], bh[4], bl[4];
#pragma unroll
    for(int m = 0; m < 4; ++m){
      int r = wm * 64 + m * 16 + l15;
      ah[m] = *(bf16x8*)&Ah[r * LDK + kb];
      al[m] = *(bf16x8*)&Al[r * LDK + kb];
    }
#pragma unroll
    for(int n = 0; n < 4; ++n){
      int c = wn * 64 + n * 16 + l15;
      bh[n] = *(bf16x8*)&Bh[c * LDK + kb];
      bl[n] = *(bf16x8*)&Bl[c * LDK + kb];
    }
#pragma unroll
    for(int m = 0; m < 4; ++m)
#pragma unroll
      for(int n = 0; n < 4; ++n){
        acc[m][n] = __builtin_amdgcn_mfma_f32_16x16x32_bf16(ah[m], bh[n], acc[m][n], 0, 0, 0);
        acc[m][n] = __builtin_amdgcn_mfma_f32_16x16x32_bf16(ah[m], bl[n], acc[m][n], 0, 0, 0);
        acc[m][n] = __builtin_amdgcn_mfma_f32_16x16x32_bf16(al[m], bh[n], acc[m][n], 0, 0, 0);
      }
  }

  // D layout: row = (lane>>4)*4 + reg, col = lane&15
#pragma unroll
  for(int n = 0; n < 4; ++n){
    int col = col0 + wn * 64 + n * 16 + l15;
    float bv = HAS_BIAS ? bias[col] : 0.f;
#pragma unroll
    for(int m = 0; m < 4; ++m){
      int rbase = row0 + wm * 64 + m * 16 + (lane >> 4) * 4;
#pragma unroll
      for(int r = 0; r < 4; ++r){
        if(rbase + r < M){
          size_t idx = (size_t)(rbase + r) * N + col;
          if(SPLITK){
            atomicAdd(&C[idx], acc[m][n][r]);
          } else {
            float val = acc[m][n][r] + bv;
            C[idx] = val;
            if(WRITE_BF16) Cb[idx] = (bf16_t)val;
          }
        }
      }
    }
  }
}

// ---------------- MFMA dual GEMM: xl and xr from one A staging ----------------
// CL = A@WL^T + biasL (+ bf16 copy), CR = A@WR^T + biasR. Tile 128x(128|128).

__global__ __launch_bounds__(256, 2) void gemm_dual_mfma_kernel(
    const float* __restrict__ A,
    const bf16_t* __restrict__ BLh, const bf16_t* __restrict__ BLl,
    const bf16_t* __restrict__ BRh, const bf16_t* __restrict__ BRl,
    const float* __restrict__ biasL, const float* __restrict__ biasR,
    float* __restrict__ CL, bf16_t* __restrict__ CLb, float* __restrict__ CR,
    int M, int Nc, int K){
  constexpr int LDK = 40;
  __shared__ bf16_t Ah[128 * LDK];
  __shared__ bf16_t Al[128 * LDK];
  __shared__ bf16_t Bh[2][128 * LDK];
  __shared__ bf16_t Bl[2][128 * LDK];

  const int tid  = threadIdx.x;
  const int lane = tid & 63;
  const int wid  = tid >> 6;
  const int wm = wid >> 1, wn = wid & 1;
  const int row0 = blockIdx.y * 128, col0 = blockIdx.x * 128;
  const int l15 = lane & 15;
  const int kb  = (lane >> 4) * 8;

  f32x4 acc[2][4][4];
#pragma unroll
  for(int s = 0; s < 2; ++s)
#pragma unroll
    for(int m = 0; m < 4; ++m)
#pragma unroll
      for(int n = 0; n < 4; ++n) acc[s][m][n] = (f32x4){0.f, 0.f, 0.f, 0.f};

  for(int k0 = 0; k0 < K; k0 += 32){
    __syncthreads();
    // A: fp32 -> hi/lo split, staged ONCE for both outputs
#pragma unroll
    for(int i = 0; i < 4; ++i){
      int f = tid + i * 256;
      int r = f >> 3, kq = f & 7;
      float4 v = make_float4(0.f, 0.f, 0.f, 0.f);
      if(row0 + r < M) v = *(const float4*)(A + (size_t)(row0 + r) * K + k0 + kq * 4);
      bf16_t h0 = (bf16_t)v.x, h1 = (bf16_t)v.y, h2 = (bf16_t)v.z, h3 = (bf16_t)v.w;
      bf16x4 hv = (bf16x4){h0, h1, h2, h3};
      bf16x4 lv = (bf16x4){(bf16_t)(v.x - (float)h0), (bf16_t)(v.y - (float)h1),
                           (bf16_t)(v.z - (float)h2), (bf16_t)(v.w - (float)h3)};
      *(bf16x4*)&Ah[r * LDK + kq * 4] = hv;
      *(bf16x4*)&Al[r * LDK + kq * 4] = lv;
    }
#pragma unroll
    for(int i = 0; i < 2; ++i){
      int f = tid + i * 256;
      int n = f >> 2, kq = f & 3;
      size_t g = (size_t)(col0 + n) * K + k0 + kq * 8;
      int lo = n * LDK + kq * 8;
      *(bf16x8*)&Bh[0][lo] = *(const bf16x8*)(BLh + g);
      *(bf16x8*)&Bl[0][lo] = *(const bf16x8*)(BLl + g);
      *(bf16x8*)&Bh[1][lo] = *(const bf16x8*)(BRh + g);
      *(bf16x8*)&Bl[1][lo] = *(const bf16x8*)(BRl + g);
    }
    __syncthreads();

    bf16x8 ah[4], al[4];
#pragma unroll
    for(int m = 0; m < 4; ++m){
      int r = wm * 64 + m * 16 + l15;
      ah[m] = *(bf16x8*)&Ah[r * LDK + kb];
      al[m] = *(bf16x8*)&Al[r * LDK + kb];
    }
#pragma unroll
    for(int s = 0; s < 2; ++s){
      bf16x8 bh[4], bl[4];
#pragma unroll
      for(int n = 0; n < 4; ++n){
        int c = wn * 64 + n * 16 + l15;
        bh[n] = *(bf16x8*)&Bh[s][c * LDK + kb];
        bl[n] = *(bf16x8*)&Bl[s][c * LDK + kb];
      }
#pragma unroll
      for(int m = 0; m < 4; ++m)
#pragma unroll
        for(int n = 0; n < 4; ++n){
          acc[s][m][n] = __builtin_amdgcn_mfma_f32_16x16x32_bf16(ah[m], bh[n], acc[s][m][n], 0, 0, 0);
          acc[s][m][n] = __builtin_amdgcn_mfma_f32_16x16x32_bf16(ah[m], bl[n], acc[s][m][n], 0, 0, 0);
          acc[s][m][n] = __builtin_amdgcn_mfma_f32_16x16x32_bf16(al[m], bh[n], acc[s][m][n], 0, 0, 0);
        }
    }
  }

#pragma unroll
  for(int n = 0; n < 4; ++n){
    int col = col0 + wn * 64 + n * 16 + l15;
    float bvL = biasL[col], bvR = biasR[col];
#pragma unroll
    for(int m = 0; m < 4; ++m){
      int rbase = row0 + wm * 64 + m * 16 + (lane >> 4) * 4;
#pragma unroll
      for(int r = 0; r < 4; ++r){
        if(rbase + r < M){
          size_t idx = (size_t)(rbase + r) * Nc + col;
          float vL = acc[0][m][n][r] + bvL;
          CL[idx]  = vL;
          CLb[idx] = (bf16_t)vL;
          CR[idx]  = acc[1][m][n][r] + bvR;
        }
      }
    }
  }
}

// ---------------- single-pass fused node kernel: one wave per node ----------------
// Online softmax over incoming edges; messages from bf16 xl values already in registers.
// Self-loop (rproj mean) folded in as final online step; exact fp32 self message.
// Layout: lane holds 8 consecutive c of head h = idx8>>4, idx8 = v*64+lane, c0=(idx8&15)*8.

__global__ void node_fused_kernel(const float* __restrict__ xl, const float* __restrict__ xr,
                                  const bf16_t* __restrict__ xlb, const bf16_t* __restrict__ rpb,
                                  const int* __restrict__ offs, const int* __restrict__ eids,
                                  const int* __restrict__ src, const int* __restrict__ rel,
                                  const float* __restrict__ att, const float* __restrict__ bias,
                                  float* __restrict__ xout, int N){
  int node = (int)((blockIdx.x * blockDim.x + threadIdx.x) >> 6);
  int lane = threadIdx.x & 63;
  if(node >= N) return;
  int beg = offs[node], end = offs[node + 1];
  float inv = 1.0f / fmaxf((float)(end - beg), 1.0f);

  const int o0 = lane * 8, o1 = (64 + lane) * 8;
  const int c0 = (lane & 15) * 8;
  f32x8 av0 = *(const f32x8*)(att + (lane >> 4) * 128 + c0);
  f32x8 av1 = *(const f32x8*)(att + (4 + (lane >> 4)) * 128 + c0);
  f32x8 xr0 = *(const f32x8*)(xr + (size_t)node * 1024 + o0);
  f32x8 xr1 = *(const f32x8*)(xr + (size_t)node * 1024 + o1);
  f32x8 xl0 = *(const f32x8*)(xl + (size_t)node * 1024 + o0);
  f32x8 xl1 = *(const f32x8*)(xl + (size_t)node * 1024 + o1);

  f32x8 lac0, lac1, num0, num1;
#pragma unroll
  for(int i = 0; i < 8; ++i){ lac0[i] = 0.f; lac1[i] = 0.f; num0[i] = 0.f; num1[i] = 0.f; }
  float m0 = -INFINITY, m1 = -INFINITY, den0 = 0.f, den1 = 0.f;

  auto online0 = [&](float res, const f32x8& msg){
    float nm = fmaxf(m0, res);
    float sc = __expf(m0 - nm), w = __expf(res - nm);
    den0 = den0 * sc + w;
#pragma unroll
    for(int i = 0; i < 8; ++i) num0[i] = num0[i] * sc + w * msg[i];
    m0 = nm;
  };
  auto online1 = [&](float res, const f32x8& msg){
    float nm = fmaxf(m1, res);
    float sc = __expf(m1 - nm), w = __expf(res - nm);
    den1 = den1 * sc + w;
#pragma unroll
    for(int i = 0; i < 8; ++i) num1[i] = num1[i] * sc + w * msg[i];
    m1 = nm;
  };

  int p = beg;
  for(; p + 1 < end; p += 2){
    int e0 = eids[p], e1 = eids[p + 1];
    int s0 = src[e0], r0 = rel[e0];
    int s1 = src[e1], r1 = rel[e1];
    const bf16_t* xs0 = xlb + (size_t)s0 * 1024;
    const bf16_t* rp0 = rpb + (size_t)r0 * 1024;
    const bf16_t* xs1 = xlb + (size_t)s1 * 1024;
    const bf16_t* rp1 = rpb + (size_t)r1 * 1024;
    bf16x8 a00 = *(const bf16x8*)(xs0 + o0), a01 = *(const bf16x8*)(xs0 + o1);
    bf16x8 b00 = *(const bf16x8*)(rp0 + o0), b01 = *(const bf16x8*)(rp0 + o1);
    bf16x8 a10 = *(const bf16x8*)(xs1 + o0), a11 = *(const bf16x8*)(xs1 + o1);
    bf16x8 b10 = *(const bf16x8*)(rp1 + o0), b11 = *(const bf16x8*)(rp1 + o1);
    float r00 = 0.f, r01 = 0.f, r10 = 0.f, r11 = 0.f;
    f32x8 f00, f01, f10, f11;
#pragma unroll
    for(int i = 0; i < 8; ++i){
      float bv;
      bv = (float)b00[i]; lac0[i] += bv; f00[i] = (float)a00[i];
      r00 += leaky(f00[i] + xr0[i] + bv) * av0[i];
      bv = (float)b01[i]; lac1[i] += bv; f01[i] = (float)a01[i];
      r01 += leaky(f01[i] + xr1[i] + bv) * av1[i];
      bv = (float)b10[i]; lac0[i] += bv; f10[i] = (float)a10[i];
      r10 += leaky(f10[i] + xr0[i] + bv) * av0[i];
      bv = (float)b11[i]; lac1[i] += bv; f11[i] = (float)a11[i];
      r11 += leaky(f11[i] + xr1[i] + bv) * av1[i];
    }
#pragma unroll
    for(int o = 8; o >= 1; o >>= 1){
      r00 += __shfl_xor(r00, o); r01 += __shfl_xor(r01, o);
      r10 += __shfl_xor(r10, o); r11 += __shfl_xor(r11, o);
    }
    online0(r00, f00); online1(r01, f01);
    online0(r10, f10); online1(r11, f11);
  }
  if(p < end){
    int e0 = eids[p];
    int s0 = src[e0], r0 = rel[e0];
    const bf16_t* xs0 = xlb + (size_t)s0 * 1024;
    const bf16_t* rp0 = rpb + (size_t)r0 * 1024;
    bf16x8 a00 = *(const bf16x8*)(xs0 + o0), a01 = *(const bf16x8*)(xs0 + o1);
    bf16x8 b00 = *(const bf16x8*)(rp0 + o0), b01 = *(const bf16x8*)(rp0 + o1);
    float r00 = 0.f, r01 = 0.f;
    f32x8 f00, f01;
#pragma unroll
    for(int i = 0; i < 8; ++i){
      float bv;
      bv = (float)b00[i]; lac0[i] += bv; f00[i] = (float)a00[i];
      r00 += leaky(f00[i] + xr0[i] + bv) * av0[i];
      bv = (float)b01[i]; lac1[i] += bv; f01[i] = (float)a01[i];
      r01 += leaky(f01[i] + xr1[i] + bv) * av1[i];
    }
#pragma unroll
    for(int o = 8; o >= 1; o >>= 1){
      r00 += __shfl_xor(r00, o); r01 += __shfl_xor(r01, o);
    }
    online0(r00, f00); online1(r01, f01);
  }

  // self loop: edge_attr = mean of incoming rproj; exact fp32 message xl[node]
  float s0 = 0.f, s1 = 0.f;
#pragma unroll
  for(int i = 0; i < 8; ++i){
    s0 += leaky(xl0[i] + xr0[i] + lac0[i] * inv) * av0[i];
    s1 += leaky(xl1[i] + xr1[i] + lac1[i] * inv) * av1[i];
  }
#pragma unroll
  for(int o = 8; o >= 1; o >>= 1){
    s0 += __shfl_xor(s0, o); s1 += __shfl_xor(s1, o);
  }
  online0(s0, xl0); online1(s1, xl1);

  // per-head normalize, sum heads (v-pair + lanes l, l+16, l+32, l+48), mean + bias
  f32x8 t;
  float d0 = 1.0f / den0, d1 = 1.0f / den1;
#pragma unroll
  for(int i = 0; i < 8; ++i) t[i] = num0[i] * d0 + num1[i] * d1;
#pragma unroll
  for(int i = 0; i < 8; ++i) t[i] += __shfl_xor(t[i], 16);
#pragma unroll
  for(int i = 0; i < 8; ++i) t[i] += __shfl_xor(t[i], 32);

  if(lane < 16){
    const float* bp = bias + lane * 8;
    float* op = xout + (size_t)node * 128 + lane * 8;
    float4 q0 = make_float4(t[0]*0.125f + bp[0], t[1]*0.125f + bp[1],
                            t[2]*0.125f + bp[2], t[3]*0.125f + bp[3]);
    float4 q1 = make_float4(t[4]*0.125f + bp[4], t[5]*0.125f + bp[5],
                            t[6]*0.125f + bp[6], t[7]*0.125f + bp[7]);
    *(float4*)op = q0;
    *(float4*)(op + 4) = q1;
  }
}

// ---------------- launch ----------------

extern "C" void kernel_launch(void* const* d_in, const int* in_sizes, int n_in,
                              void* d_out, int out_size, void* d_ws, size_t ws_size,
                              hipStream_t stream){
  const float* x0   = (const float*)d_in[0];
  const int*   ei   = (const int*)d_in[1];
  const float* rel0 = (const float*)d_in[2];
  const int*   ridx = (const int*)d_in[3];
  const float* Wl   = (const float*)d_in[4];
  const float* bl   = (const float*)d_in[5];
  const float* Wr   = (const float*)d_in[6];
  const float* br   = (const float*)d_in[7];
  const float* We   = (const float*)d_in[8];
  const float* att  = (const float*)d_in[9];
  const float* bias = (const float*)d_in[10];
  const float* Wb   = (const float*)d_in[11];
  const float* bb   = (const float*)d_in[12];

  const int D = 128, HC = 1024;
  const int N = in_sizes[0] / D;
  const int E = in_sizes[1] / 2;
  const int R = in_sizes[2] / D;
  const int WSZ = D * HC;

  const int* src = ei;
  const int* dst = ei + E;

  char* ws = (char*)d_ws;
  size_t off = 0;
  auto alloc = [&](size_t bytes) -> void* {
    void* p = ws + off;
    off += (bytes + 255) & ~(size_t)255;
    return p;
  };
  float*  xl     = (float*)alloc((size_t)N * HC * 4);
  float*  xr     = (float*)alloc((size_t)N * HC * 4);
  float*  rproj  = (float*)alloc((size_t)R * HC * 4);
  bf16_t* xlb    = (bf16_t*)alloc((size_t)N * HC * 2);
  bf16_t* rpb    = (bf16_t*)alloc((size_t)R * HC * 2);
  float*  xbufA  = (float*)alloc((size_t)N * D * 4);
  float*  xbufB  = (float*)alloc((size_t)N * D * 4);
  float*  rbufA  = (float*)alloc((size_t)R * D * 4);
  float*  rbufB  = (float*)alloc((size_t)R * D * 4);
  int* deg    = (int*)alloc((size_t)N * 4);
  int* offs   = (int*)alloc((size_t)(N + 1) * 4);
  int* cursor = (int*)alloc((size_t)N * 4);
  int* eids   = (int*)alloc((size_t)E * 4);
  bf16_t* tWl_h = (bf16_t*)alloc((size_t)N_LAYERS * WSZ * 2);
  bf16_t* tWl_l = (bf16_t*)alloc((size_t)N_LAYERS * WSZ * 2);
  bf16_t* tWr_h = (bf16_t*)alloc((size_t)N_LAYERS * WSZ * 2);
  bf16_t* tWr_l = (bf16_t*)alloc((size_t)N_LAYERS * WSZ * 2);
  bf16_t* tWe_h = (bf16_t*)alloc((size_t)N_LAYERS * WSZ * 2);
  bf16_t* tWe_l = (bf16_t*)alloc((size_t)N_LAYERS * WSZ * 2);
  bf16_t* tWb_h = (bf16_t*)alloc((size_t)N_LAYERS * WSZ * 2);
  bf16_t* tWb_l = (bf16_t*)alloc((size_t)N_LAYERS * WSZ * 2);
  float* xbuf[2] = {xbufA, xbufB};
  float* rbuf[2] = {rbufA, rbufB};

  float* out_x = (float*)d_out;
  float* out_r = (float*)d_out + (size_t)N * D;

  // CSR build (once; edge structure is layer-invariant)
  fill_int_kernel<<<(N + 255) / 256, 256, 0, stream>>>(deg, 0, N);
  fill_int_kernel<<<(N + 255) / 256, 256, 0, stream>>>(cursor, 0, N);
  hist_kernel<<<(E + 255) / 256, 256, 0, stream>>>(dst, E, deg);
  scan_kernel<<<1, 256, 0, stream>>>(deg, offs, N);
  scatter_kernel<<<(E + 255) / 256, 256, 0, stream>>>(dst, E, offs, cursor, eids);

  // weight prep: transpose + hi/lo split (all layers, upfront)
  dim3 tblk(32, 8);
  for(int l = 0; l < N_LAYERS; ++l){
    size_t wo = (size_t)l * WSZ;
    transpose_split_kernel<<<dim3(D/32, HC/32), tblk, 0, stream>>>(Wl + wo, tWl_h + wo, tWl_l + wo, D, HC);
    transpose_split_kernel<<<dim3(D/32, HC/32), tblk, 0, stream>>>(Wr + wo, tWr_h + wo, tWr_l + wo, D, HC);
    transpose_split_kernel<<<dim3(D/32, HC/32), tblk, 0, stream>>>(We + wo, tWe_h + wo, tWe_l + wo, D, HC);
    transpose_split_kernel<<<dim3(HC/32, D/32), tblk, 0, stream>>>(Wb + wo, tWb_h + wo, tWb_l + wo, HC, D);
  }

  for(int l = 0; l < N_LAYERS; ++l){
    const float* xin = (l == 0) ? x0   : xbuf[(l + 1) & 1];
    float*       xo  = (l == N_LAYERS - 1) ? out_x : xbuf[l & 1];
    const float* rin = (l == 0) ? rel0 : rbuf[(l + 1) & 1];
    float*       ro  = (l == N_LAYERS - 1) ? out_r : rbuf[l & 1];
    size_t wo = (size_t)l * WSZ;
    const float* bl_l  = bl + (size_t)l * HC;
    const float* br_l  = br + (size_t)l * HC;
    const float* att_l = att + (size_t)l * 8 * 128;
    const float* bias_l= bias + (size_t)l * D;
    const float* bb_l  = bb + (size_t)l * D;

    // rproj = relations @ We (no bias) + bf16 copy
    gemm_mfma_kernel<false,false,true,false><<<dim3(HC/128, (R+127)/128), 256, 0, stream>>>(
        rin, tWe_h + wo, tWe_l + wo, nullptr, rproj, rpb, R, HC, D);
    // fused xl/xr: A staged once
    gemm_dual_mfma_kernel<<<dim3(HC/128, (N+127)/128), 256, 0, stream>>>(
        xin, tWl_h + wo, tWl_l + wo, tWr_h + wo, tWr_l + wo,
        bl_l, br_l, xl, xlb, xr, N, HC, D);
    // single-pass fused node kernel
    node_fused_kernel<<<(N * 64 + 255) / 256, 256, 0, stream>>>(
        xl, xr, xlb, rpb, offs, eids, src, ridx, att_l, bias_l, xo, N);
    // relation update: ro = relu(rproj) @ Wb + bb, split-K over 8 slices
    fill_bias_kernel<<<(R * 128 + 255) / 256, 256, 0, stream>>>(ro, bb_l, R);
    gemm_mfma_kernel<true,false,false,true><<<dim3(D/128, (R+127)/128, 8), 256, 0, stream>>>(
        rproj, tWb_h + wo, tWb_l + wo, nullptr, ro, nullptr, R, D, HC);
  }
}

// Round 5
// 588.984 us; speedup vs baseline: 1.5780x; 1.5780x over previous
//
#include <hip/hip_runtime.h>
#include <hip/hip_bf16.h>
#include <math.h>

#define NEG_SLOPE 0.2f
#define N_LAYERS 4

typedef __bf16 bf16_t;
typedef __attribute__((ext_vector_type(8))) __bf16 bf16x8;
typedef __attribute__((ext_vector_type(4))) __bf16 bf16x4;
typedef __attribute__((ext_vector_type(4))) float f32x4;
typedef __attribute__((ext_vector_type(8))) float f32x8;

static __device__ __forceinline__ float leaky(float v){ return v > 0.f ? v : NEG_SLOPE * v; }

// ---------------- CSR build (edge structure fixed across layers) ----------------

__global__ void fill_int_kernel(int* __restrict__ p, int v, int n){
  int i = blockIdx.x*blockDim.x + threadIdx.x;
  if(i < n) p[i] = v;
}

__global__ void fill_bias_kernel(float* __restrict__ out, const float* __restrict__ b, int rows){
  int i = blockIdx.x*blockDim.x + threadIdx.x;
  if(i < rows * 128) out[i] = b[i & 127];
}

__global__ void hist_kernel(const int* __restrict__ dst, int E, int* __restrict__ deg){
  int e = blockIdx.x*blockDim.x + threadIdx.x;
  if(e < E) atomicAdd(&deg[dst[e]], 1);
}

// exclusive scan via wave shuffles: offs[0]=0, offs[i+1]=sum(deg[0..i]). One block, 256 thr.
__global__ void scan_kernel(const int* __restrict__ deg, int* __restrict__ offs, int N){
  __shared__ int wsum[4];
  int t = threadIdx.x, lane = t & 63, w = t >> 6;
  int carry = 0;
  for(int base = 0; base < N; base += 256){
    int v = (base + t < N) ? deg[base + t] : 0;
    int s = v;
#pragma unroll
    for(int o = 1; o < 64; o <<= 1){
      int u = __shfl_up(s, o);
      if(lane >= o) s += u;
    }
    if(lane == 63) wsum[w] = s;
    __syncthreads();
    int woff = 0;
    for(int i = 0; i < w; ++i) woff += wsum[i];
    if(base + t < N) offs[base + t + 1] = carry + woff + s;
    int tot = wsum[0] + wsum[1] + wsum[2] + wsum[3];
    __syncthreads();
    carry += tot;
  }
  if(t == 0) offs[0] = 0;
}

__global__ void scatter_kernel(const int* __restrict__ dst, int E,
                               const int* __restrict__ offs, int* __restrict__ cursor,
                               int* __restrict__ eids){
  int e = blockIdx.x*blockDim.x + threadIdx.x;
  if(e < E){
    int d = dst[e];
    int pos = offs[d] + atomicAdd(&cursor[d], 1);
    eids[pos] = e;
  }
}

// ---------------- weight transpose + bf16 hi/lo split ----------------

__global__ void transpose_split_kernel(const float* __restrict__ W,
                                       bf16_t* __restrict__ Th, bf16_t* __restrict__ Tl,
                                       int K, int N){
  __shared__ float t[32][33];
  int k0 = blockIdx.x * 32, n0 = blockIdx.y * 32;
  int tx = threadIdx.x, ty = threadIdx.y;
#pragma unroll
  for(int i = 0; i < 4; ++i)
    t[ty*4 + i][tx] = W[(size_t)(k0 + ty*4 + i) * N + n0 + tx];
  __syncthreads();
#pragma unroll
  for(int i = 0; i < 4; ++i){
    int n = ty*4 + i;
    float v = t[tx][n];
    bf16_t h = (bf16_t)v;
    bf16_t l = (bf16_t)(v - (float)h);
    Th[(size_t)(n0 + n) * K + k0 + tx] = h;
    Tl[(size_t)(n0 + n) * K + k0 + tx] = l;
  }
}

// ---------------- MFMA split-bf16 GEMM (single output) ----------------

template<bool RELU_A, bool HAS_BIAS, bool WRITE_BF16, bool SPLITK>
__global__ __launch_bounds__(256) void gemm_mfma_kernel(
    const float* __restrict__ A,
    const bf16_t* __restrict__ Bt_hi, const bf16_t* __restrict__ Bt_lo,
    const float* __restrict__ bias, float* __restrict__ C, bf16_t* __restrict__ Cb,
    int M, int N, int K){
  constexpr int LDK = 40;
  __shared__ bf16_t Ah[128 * LDK];
  __shared__ bf16_t Al[128 * LDK];
  __shared__ bf16_t Bh[128 * LDK];
  __shared__ bf16_t Bl[128 * LDK];

  const int tid  = threadIdx.x;
  const int lane = tid & 63;
  const int wid  = tid >> 6;
  const int wm = wid >> 1, wn = wid & 1;
  const int row0 = blockIdx.y * 128, col0 = blockIdx.x * 128;
  const int l15 = lane & 15;
  const int kb  = (lane >> 4) * 8;

  f32x4 acc[4][4];
#pragma unroll
  for(int m = 0; m < 4; ++m)
#pragma unroll
    for(int n = 0; n < 4; ++n) acc[m][n] = (f32x4){0.f, 0.f, 0.f, 0.f};

  int kbeg = 0, kend = K;
  if(SPLITK){ kbeg = blockIdx.z * 128; kend = kbeg + 128; }

  for(int k0 = kbeg; k0 < kend; k0 += 32){
    __syncthreads();
#pragma unroll
    for(int i = 0; i < 4; ++i){
      int f = tid + i * 256;
      int r = f >> 3, kq = f & 7;
      float4 v = make_float4(0.f, 0.f, 0.f, 0.f);
      if(row0 + r < M) v = *(const float4*)(A + (size_t)(row0 + r) * K + k0 + kq * 4);
      if(RELU_A){ v.x = fmaxf(v.x, 0.f); v.y = fmaxf(v.y, 0.f); v.z = fmaxf(v.z, 0.f); v.w = fmaxf(v.w, 0.f); }
      bf16_t h0 = (bf16_t)v.x, h1 = (bf16_t)v.y, h2 = (bf16_t)v.z, h3 = (bf16_t)v.w;
      bf16x4 hv = (bf16x4){h0, h1, h2, h3};
      bf16x4 lv = (bf16x4){(bf16_t)(v.x - (float)h0), (bf16_t)(v.y - (float)h1),
                           (bf16_t)(v.z - (float)h2), (bf16_t)(v.w - (float)h3)};
      *(bf16x4*)&Ah[r * LDK + kq * 4] = hv;
      *(bf16x4*)&Al[r * LDK + kq * 4] = lv;
    }
#pragma unroll
    for(int i = 0; i < 2; ++i){
      int f = tid + i * 256;
      int n = f >> 2, kq = f & 3;
      *(bf16x8*)&Bh[n * LDK + kq * 8] = *(const bf16x8*)(Bt_hi + (size_t)(col0 + n) * K + k0 + kq * 8);
      *(bf16x8*)&Bl[n * LDK + kq * 8] = *(const bf16x8*)(Bt_lo + (size_t)(col0 + n) * K + k0 + kq * 8);
    }
    __syncthreads();

    bf16x8 ah[4], al[4], bh[4], bl[4];
#pragma unroll
    for(int m = 0; m < 4; ++m){
      int r = wm * 64 + m * 16 + l15;
      ah[m] = *(bf16x8*)&Ah[r * LDK + kb];
      al[m] = *(bf16x8*)&Al[r * LDK + kb];
    }
#pragma unroll
    for(int n = 0; n < 4; ++n){
      int c = wn * 64 + n * 16 + l15;
      bh[n] = *(bf16x8*)&Bh[c * LDK + kb];
      bl[n] = *(bf16x8*)&Bl[c * LDK + kb];
    }
#pragma unroll
    for(int m = 0; m < 4; ++m)
#pragma unroll
      for(int n = 0; n < 4; ++n){
        acc[m][n] = __builtin_amdgcn_mfma_f32_16x16x32_bf16(ah[m], bh[n], acc[m][n], 0, 0, 0);
        acc[m][n] = __builtin_amdgcn_mfma_f32_16x16x32_bf16(ah[m], bl[n], acc[m][n], 0, 0, 0);
        acc[m][n] = __builtin_amdgcn_mfma_f32_16x16x32_bf16(al[m], bh[n], acc[m][n], 0, 0, 0);
      }
  }

  // D layout: row = (lane>>4)*4 + reg, col = lane&15
#pragma unroll
  for(int n = 0; n < 4; ++n){
    int col = col0 + wn * 64 + n * 16 + l15;
    float bv = HAS_BIAS ? bias[col] : 0.f;
#pragma unroll
    for(int m = 0; m < 4; ++m){
      int rbase = row0 + wm * 64 + m * 16 + (lane >> 4) * 4;
#pragma unroll
      for(int r = 0; r < 4; ++r){
        if(rbase + r < M){
          size_t idx = (size_t)(rbase + r) * N + col;
          if(SPLITK){
            atomicAdd(&C[idx], acc[m][n][r]);
          } else {
            float val = acc[m][n][r] + bv;
            C[idx] = val;
            if(WRITE_BF16) Cb[idx] = (bf16_t)val;
          }
        }
      }
    }
  }
}

// ---------------- MFMA dual GEMM: xl and xr from one A staging ----------------

__global__ __launch_bounds__(256, 2) void gemm_dual_mfma_kernel(
    const float* __restrict__ A,
    const bf16_t* __restrict__ BLh, const bf16_t* __restrict__ BLl,
    const bf16_t* __restrict__ BRh, const bf16_t* __restrict__ BRl,
    const float* __restrict__ biasL, const float* __restrict__ biasR,
    float* __restrict__ CL, bf16_t* __restrict__ CLb, float* __restrict__ CR,
    int M, int Nc, int K){
  constexpr int LDK = 40;
  __shared__ bf16_t Ah[128 * LDK];
  __shared__ bf16_t Al[128 * LDK];
  __shared__ bf16_t Bh[2][128 * LDK];
  __shared__ bf16_t Bl[2][128 * LDK];

  const int tid  = threadIdx.x;
  const int lane = tid & 63;
  const int wid  = tid >> 6;
  const int wm = wid >> 1, wn = wid & 1;
  const int row0 = blockIdx.y * 128, col0 = blockIdx.x * 128;
  const int l15 = lane & 15;
  const int kb  = (lane >> 4) * 8;

  f32x4 acc[2][4][4];
#pragma unroll
  for(int s = 0; s < 2; ++s)
#pragma unroll
    for(int m = 0; m < 4; ++m)
#pragma unroll
      for(int n = 0; n < 4; ++n) acc[s][m][n] = (f32x4){0.f, 0.f, 0.f, 0.f};

  for(int k0 = 0; k0 < K; k0 += 32){
    __syncthreads();
#pragma unroll
    for(int i = 0; i < 4; ++i){
      int f = tid + i * 256;
      int r = f >> 3, kq = f & 7;
      float4 v = make_float4(0.f, 0.f, 0.f, 0.f);
      if(row0 + r < M) v = *(const float4*)(A + (size_t)(row0 + r) * K + k0 + kq * 4);
      bf16_t h0 = (bf16_t)v.x, h1 = (bf16_t)v.y, h2 = (bf16_t)v.z, h3 = (bf16_t)v.w;
      bf16x4 hv = (bf16x4){h0, h1, h2, h3};
      bf16x4 lv = (bf16x4){(bf16_t)(v.x - (float)h0), (bf16_t)(v.y - (float)h1),
                           (bf16_t)(v.z - (float)h2), (bf16_t)(v.w - (float)h3)};
      *(bf16x4*)&Ah[r * LDK + kq * 4] = hv;
      *(bf16x4*)&Al[r * LDK + kq * 4] = lv;
    }
#pragma unroll
    for(int i = 0; i < 2; ++i){
      int f = tid + i * 256;
      int n = f >> 2, kq = f & 3;
      size_t g = (size_t)(col0 + n) * K + k0 + kq * 8;
      int lo = n * LDK + kq * 8;
      *(bf16x8*)&Bh[0][lo] = *(const bf16x8*)(BLh + g);
      *(bf16x8*)&Bl[0][lo] = *(const bf16x8*)(BLl + g);
      *(bf16x8*)&Bh[1][lo] = *(const bf16x8*)(BRh + g);
      *(bf16x8*)&Bl[1][lo] = *(const bf16x8*)(BRl + g);
    }
    __syncthreads();

    bf16x8 ah[4], al[4];
#pragma unroll
    for(int m = 0; m < 4; ++m){
      int r = wm * 64 + m * 16 + l15;
      ah[m] = *(bf16x8*)&Ah[r * LDK + kb];
      al[m] = *(bf16x8*)&Al[r * LDK + kb];
    }
#pragma unroll
    for(int s = 0; s < 2; ++s){
      bf16x8 bh[4], bl[4];
#pragma unroll
      for(int n = 0; n < 4; ++n){
        int c = wn * 64 + n * 16 + l15;
        bh[n] = *(bf16x8*)&Bh[s][c * LDK + kb];
        bl[n] = *(bf16x8*)&Bl[s][c * LDK + kb];
      }
#pragma unroll
      for(int m = 0; m < 4; ++m)
#pragma unroll
        for(int n = 0; n < 4; ++n){
          acc[s][m][n] = __builtin_amdgcn_mfma_f32_16x16x32_bf16(ah[m], bh[n], acc[s][m][n], 0, 0, 0);
          acc[s][m][n] = __builtin_amdgcn_mfma_f32_16x16x32_bf16(ah[m], bl[n], acc[s][m][n], 0, 0, 0);
          acc[s][m][n] = __builtin_amdgcn_mfma_f32_16x16x32_bf16(al[m], bh[n], acc[s][m][n], 0, 0, 0);
        }
    }
  }

#pragma unroll
  for(int n = 0; n < 4; ++n){
    int col = col0 + wn * 64 + n * 16 + l15;
    float bvL = biasL[col], bvR = biasR[col];
#pragma unroll
    for(int m = 0; m < 4; ++m){
      int rbase = row0 + wm * 64 + m * 16 + (lane >> 4) * 4;
#pragma unroll
      for(int r = 0; r < 4; ++r){
        if(rbase + r < M){
          size_t idx = (size_t)(rbase + r) * Nc + col;
          float vL = acc[0][m][n][r] + bvL;
          CL[idx]  = vL;
          CLb[idx] = (bf16_t)vL;
          CR[idx]  = acc[1][m][n][r] + bvR;
        }
      }
    }
  }
}

// ---------------- single-pass fused node kernel: one wave per node ----------------
// Online softmax over incoming edges; messages are the bf16 xl[src] values already
// loaded for the logit. NO lambdas / address-taken state (R4 scratch-spill lesson):
// all accumulators are named locals updated by explicit inline blocks.

__global__ __launch_bounds__(256) void node_fused_kernel(
    const float* __restrict__ xl, const float* __restrict__ xr,
    const bf16_t* __restrict__ xlb, const bf16_t* __restrict__ rpb,
    const int* __restrict__ offs, const int* __restrict__ eids,
    const int* __restrict__ src, const int* __restrict__ rel,
    const float* __restrict__ att, const float* __restrict__ bias,
    float* __restrict__ xout, int N){
  int node = (int)((blockIdx.x * blockDim.x + threadIdx.x) >> 6);
  int lane = threadIdx.x & 63;
  if(node >= N) return;
  int beg = offs[node], end = offs[node + 1];
  float inv = 1.0f / fmaxf((float)(end - beg), 1.0f);

  const int o0 = lane * 8, o1 = (64 + lane) * 8;
  const int c0 = (lane & 15) * 8;
  f32x8 av0 = *(const f32x8*)(att + (lane >> 4) * 128 + c0);
  f32x8 av1 = *(const f32x8*)(att + (4 + (lane >> 4)) * 128 + c0);
  f32x8 xr0 = *(const f32x8*)(xr + (size_t)node * 1024 + o0);
  f32x8 xr1 = *(const f32x8*)(xr + (size_t)node * 1024 + o1);

  f32x8 lac0, lac1, num0, num1;
#pragma unroll
  for(int i = 0; i < 8; ++i){ lac0[i] = 0.f; lac1[i] = 0.f; num0[i] = 0.f; num1[i] = 0.f; }
  float m0 = -INFINITY, m1 = -INFINITY, den0 = 0.f, den1 = 0.f;

  for(int p = beg; p < end; ++p){
    int e = eids[p];
    int s = src[e], r = rel[e];
    const bf16_t* xs = xlb + (size_t)s * 1024;
    const bf16_t* rp = rpb + (size_t)r * 1024;
    bf16x8 a0 = *(const bf16x8*)(xs + o0), a1 = *(const bf16x8*)(xs + o1);
    bf16x8 b0 = *(const bf16x8*)(rp + o0), b1 = *(const bf16x8*)(rp + o1);
    f32x8 f0, f1;
    float r0 = 0.f, r1 = 0.f;
#pragma unroll
    for(int i = 0; i < 8; ++i){
      float bv0 = (float)b0[i]; lac0[i] += bv0; f0[i] = (float)a0[i];
      r0 += leaky(f0[i] + xr0[i] + bv0) * av0[i];
      float bv1 = (float)b1[i]; lac1[i] += bv1; f1[i] = (float)a1[i];
      r1 += leaky(f1[i] + xr1[i] + bv1) * av1[i];
    }
#pragma unroll
    for(int o = 8; o >= 1; o >>= 1){
      r0 += __shfl_xor(r0, o);
      r1 += __shfl_xor(r1, o);
    }
    // online update, head-group 0 (explicit, no lambda)
    {
      float nm = fmaxf(m0, r0);
      float sc = __expf(m0 - nm), w = __expf(r0 - nm);
      den0 = den0 * sc + w;
#pragma unroll
      for(int i = 0; i < 8; ++i) num0[i] = num0[i] * sc + w * f0[i];
      m0 = nm;
    }
    // online update, head-group 1
    {
      float nm = fmaxf(m1, r1);
      float sc = __expf(m1 - nm), w = __expf(r1 - nm);
      den1 = den1 * sc + w;
#pragma unroll
      for(int i = 0; i < 8; ++i) num1[i] = num1[i] * sc + w * f1[i];
      m1 = nm;
    }
  }

  // self loop: edge_attr = mean of incoming rproj; exact fp32 self message
  f32x8 xl0 = *(const f32x8*)(xl + (size_t)node * 1024 + o0);
  f32x8 xl1 = *(const f32x8*)(xl + (size_t)node * 1024 + o1);
  float s0 = 0.f, s1 = 0.f;
#pragma unroll
  for(int i = 0; i < 8; ++i){
    s0 += leaky(xl0[i] + xr0[i] + lac0[i] * inv) * av0[i];
    s1 += leaky(xl1[i] + xr1[i] + lac1[i] * inv) * av1[i];
  }
#pragma unroll
  for(int o = 8; o >= 1; o >>= 1){
    s0 += __shfl_xor(s0, o);
    s1 += __shfl_xor(s1, o);
  }
  {
    float nm = fmaxf(m0, s0);
    float sc = __expf(m0 - nm), w = __expf(s0 - nm);
    den0 = den0 * sc + w;
#pragma unroll
    for(int i = 0; i < 8; ++i) num0[i] = num0[i] * sc + w * xl0[i];
    m0 = nm;
  }
  {
    float nm = fmaxf(m1, s1);
    float sc = __expf(m1 - nm), w = __expf(s1 - nm);
    den1 = den1 * sc + w;
#pragma unroll
    for(int i = 0; i < 8; ++i) num1[i] = num1[i] * sc + w * xl1[i];
    m1 = nm;
  }

  // per-head normalize, sum 8 heads (2 per lane x lanes l, l^16, l^32+...), mean + bias
  f32x8 t;
  float d0 = 1.0f / den0, d1 = 1.0f / den1;
#pragma unroll
  for(int i = 0; i < 8; ++i) t[i] = num0[i] * d0 + num1[i] * d1;
#pragma unroll
  for(int i = 0; i < 8; ++i) t[i] += __shfl_xor(t[i], 16);
#pragma unroll
  for(int i = 0; i < 8; ++i) t[i] += __shfl_xor(t[i], 32);

  if(lane < 16){
    const float* bp = bias + lane * 8;
    float* op = xout + (size_t)node * 128 + lane * 8;
    float4 q0 = make_float4(t[0]*0.125f + bp[0], t[1]*0.125f + bp[1],
                            t[2]*0.125f + bp[2], t[3]*0.125f + bp[3]);
    float4 q1 = make_float4(t[4]*0.125f + bp[4], t[5]*0.125f + bp[5],
                            t[6]*0.125f + bp[6], t[7]*0.125f + bp[7]);
    *(float4*)op = q0;
    *(float4*)(op + 4) = q1;
  }
}

// ---------------- launch ----------------

extern "C" void kernel_launch(void* const* d_in, const int* in_sizes, int n_in,
                              void* d_out, int out_size, void* d_ws, size_t ws_size,
                              hipStream_t stream){
  const float* x0   = (const float*)d_in[0];
  const int*   ei   = (const int*)d_in[1];
  const float* rel0 = (const float*)d_in[2];
  const int*   ridx = (const int*)d_in[3];
  const float* Wl   = (const float*)d_in[4];
  const float* bl   = (const float*)d_in[5];
  const float* Wr   = (const float*)d_in[6];
  const float* br   = (const float*)d_in[7];
  const float* We   = (const float*)d_in[8];
  const float* att  = (const float*)d_in[9];
  const float* bias = (const float*)d_in[10];
  const float* Wb   = (const float*)d_in[11];
  const float* bb   = (const float*)d_in[12];

  const int D = 128, HC = 1024;
  const int N = in_sizes[0] / D;
  const int E = in_sizes[1] / 2;
  const int R = in_sizes[2] / D;
  const int WSZ = D * HC;

  const int* src = ei;
  const int* dst = ei + E;

  char* ws = (char*)d_ws;
  size_t off = 0;
  auto alloc = [&](size_t bytes) -> void* {
    void* p = ws + off;
    off += (bytes + 255) & ~(size_t)255;
    return p;
  };
  float*  xl     = (float*)alloc((size_t)N * HC * 4);
  float*  xr     = (float*)alloc((size_t)N * HC * 4);
  float*  rproj  = (float*)alloc((size_t)R * HC * 4);
  bf16_t* xlb    = (bf16_t*)alloc((size_t)N * HC * 2);
  bf16_t* rpb    = (bf16_t*)alloc((size_t)R * HC * 2);
  float*  xbufA  = (float*)alloc((size_t)N * D * 4);
  float*  xbufB  = (float*)alloc((size_t)N * D * 4);
  float*  rbufA  = (float*)alloc((size_t)R * D * 4);
  float*  rbufB  = (float*)alloc((size_t)R * D * 4);
  int* deg    = (int*)alloc((size_t)N * 4);
  int* offs   = (int*)alloc((size_t)(N + 1) * 4);
  int* cursor = (int*)alloc((size_t)N * 4);
  int* eids   = (int*)alloc((size_t)E * 4);
  bf16_t* tWl_h = (bf16_t*)alloc((size_t)N_LAYERS * WSZ * 2);
  bf16_t* tWl_l = (bf16_t*)alloc((size_t)N_LAYERS * WSZ * 2);
  bf16_t* tWr_h = (bf16_t*)alloc((size_t)N_LAYERS * WSZ * 2);
  bf16_t* tWr_l = (bf16_t*)alloc((size_t)N_LAYERS * WSZ * 2);
  bf16_t* tWe_h = (bf16_t*)alloc((size_t)N_LAYERS * WSZ * 2);
  bf16_t* tWe_l = (bf16_t*)alloc((size_t)N_LAYERS * WSZ * 2);
  bf16_t* tWb_h = (bf16_t*)alloc((size_t)N_LAYERS * WSZ * 2);
  bf16_t* tWb_l = (bf16_t*)alloc((size_t)N_LAYERS * WSZ * 2);
  float* xbuf[2] = {xbufA, xbufB};
  float* rbuf[2] = {rbufA, rbufB};

  float* out_x = (float*)d_out;
  float* out_r = (float*)d_out + (size_t)N * D;

  // CSR build (once; edge structure is layer-invariant)
  fill_int_kernel<<<(N + 255) / 256, 256, 0, stream>>>(deg, 0, N);
  fill_int_kernel<<<(N + 255) / 256, 256, 0, stream>>>(cursor, 0, N);
  hist_kernel<<<(E + 255) / 256, 256, 0, stream>>>(dst, E, deg);
  scan_kernel<<<1, 256, 0, stream>>>(deg, offs, N);
  scatter_kernel<<<(E + 255) / 256, 256, 0, stream>>>(dst, E, offs, cursor, eids);

  // weight prep: transpose + hi/lo split (all layers, upfront)
  dim3 tblk(32, 8);
  for(int l = 0; l < N_LAYERS; ++l){
    size_t wo = (size_t)l * WSZ;
    transpose_split_kernel<<<dim3(D/32, HC/32), tblk, 0, stream>>>(Wl + wo, tWl_h + wo, tWl_l + wo, D, HC);
    transpose_split_kernel<<<dim3(D/32, HC/32), tblk, 0, stream>>>(Wr + wo, tWr_h + wo, tWr_l + wo, D, HC);
    transpose_split_kernel<<<dim3(D/32, HC/32), tblk, 0, stream>>>(We + wo, tWe_h + wo, tWe_l + wo, D, HC);
    transpose_split_kernel<<<dim3(HC/32, D/32), tblk, 0, stream>>>(Wb + wo, tWb_h + wo, tWb_l + wo, HC, D);
  }

  for(int l = 0; l < N_LAYERS; ++l){
    const float* xin = (l == 0) ? x0   : xbuf[(l + 1) & 1];
    float*       xo  = (l == N_LAYERS - 1) ? out_x : xbuf[l & 1];
    const float* rin = (l == 0) ? rel0 : rbuf[(l + 1) & 1];
    float*       ro  = (l == N_LAYERS - 1) ? out_r : rbuf[l & 1];
    size_t wo = (size_t)l * WSZ;
    const float* bl_l  = bl + (size_t)l * HC;
    const float* br_l  = br + (size_t)l * HC;
    const float* att_l = att + (size_t)l * 8 * 128;
    const float* bias_l= bias + (size_t)l * D;
    const float* bb_l  = bb + (size_t)l * D;

    // rproj = relations @ We (no bias) + bf16 copy
    gemm_mfma_kernel<false,false,true,false><<<dim3(HC/128, (R+127)/128), 256, 0, stream>>>(
        rin, tWe_h + wo, tWe_l + wo, nullptr, rproj, rpb, R, HC, D);
    // fused xl/xr: A staged once
    gemm_dual_mfma_kernel<<<dim3(HC/128, (N+127)/128), 256, 0, stream>>>(
        xin, tWl_h + wo, tWl_l + wo, tWr_h + wo, tWr_l + wo,
        bl_l, br_l, xl, xlb, xr, N, HC, D);
    // single-pass fused node kernel
    node_fused_kernel<<<(N * 64 + 255) / 256, 256, 0, stream>>>(
        xl, xr, xlb, rpb, offs, eids, src, ridx, att_l, bias_l, xo, N);
    // relation update: ro = relu(rproj) @ Wb + bb, split-K over 8 slices
    fill_bias_kernel<<<(R * 128 + 255) / 256, 256, 0, stream>>>(ro, bb_l, R);
    gemm_mfma_kernel<true,false,false,true><<<dim3(D/128, (R+127)/128, 8), 256, 0, stream>>>(
        rproj, tWb_h + wo, tWb_l + wo, nullptr, ro, nullptr, R, D, HC);
  }
}

// Round 6
// 584.736 us; speedup vs baseline: 1.5895x; 1.0073x over previous
//
#include <hip/hip_runtime.h>
#include <hip/hip_bf16.h>
#include <math.h>

#define NEG_SLOPE 0.2f
#define N_LAYERS 4

typedef __bf16 bf16_t;
typedef __attribute__((ext_vector_type(8))) __bf16 bf16x8;
typedef __attribute__((ext_vector_type(4))) __bf16 bf16x4;
typedef __attribute__((ext_vector_type(4))) float f32x4;
typedef __attribute__((ext_vector_type(8))) float f32x8;

static __device__ __forceinline__ float leaky(float v){ return v > 0.f ? v : NEG_SLOPE * v; }

// ---------------- CSR build (edge structure fixed across layers) ----------------

__global__ void fill_int_kernel(int* __restrict__ p, int v, int n){
  int i = blockIdx.x*blockDim.x + threadIdx.x;
  if(i < n) p[i] = v;
}

__global__ void fill_bias_kernel(float* __restrict__ out, const float* __restrict__ b, int rows){
  int i = blockIdx.x*blockDim.x + threadIdx.x;
  if(i < rows * 128) out[i] = b[i & 127];
}

__global__ void hist_kernel(const int* __restrict__ dst, int E, int* __restrict__ deg){
  int e = blockIdx.x*blockDim.x + threadIdx.x;
  if(e < E) atomicAdd(&deg[dst[e]], 1);
}

// exclusive scan via wave shuffles: offs[0]=0, offs[i+1]=sum(deg[0..i]). One block, 256 thr.
__global__ void scan_kernel(const int* __restrict__ deg, int* __restrict__ offs, int N){
  __shared__ int wsum[4];
  int t = threadIdx.x, lane = t & 63, w = t >> 6;
  int carry = 0;
  for(int base = 0; base < N; base += 256){
    int v = (base + t < N) ? deg[base + t] : 0;
    int s = v;
#pragma unroll
    for(int o = 1; o < 64; o <<= 1){
      int u = __shfl_up(s, o);
      if(lane >= o) s += u;
    }
    if(lane == 63) wsum[w] = s;
    __syncthreads();
    int woff = 0;
    for(int i = 0; i < w; ++i) woff += wsum[i];
    if(base + t < N) offs[base + t + 1] = carry + woff + s;
    int tot = wsum[0] + wsum[1] + wsum[2] + wsum[3];
    __syncthreads();
    carry += tot;
  }
  if(t == 0) offs[0] = 0;
}

// scatter src/rel permuted by CSR position (drops one indirection in the node loop)
__global__ void scatter_kernel(const int* __restrict__ src, const int* __restrict__ dst,
                               const int* __restrict__ rel, int E,
                               const int* __restrict__ offs, int* __restrict__ cursor,
                               int* __restrict__ srcs, int* __restrict__ rels){
  int e = blockIdx.x*blockDim.x + threadIdx.x;
  if(e < E){
    int d = dst[e];
    int pos = offs[d] + atomicAdd(&cursor[d], 1);
    srcs[pos] = src[e];
    rels[pos] = rel[e];
  }
}

// ---------------- weight transpose + bf16 hi/lo split ----------------

__global__ void transpose_split_kernel(const float* __restrict__ W,
                                       bf16_t* __restrict__ Th, bf16_t* __restrict__ Tl,
                                       int K, int N){
  __shared__ float t[32][33];
  int k0 = blockIdx.x * 32, n0 = blockIdx.y * 32;
  int tx = threadIdx.x, ty = threadIdx.y;
#pragma unroll
  for(int i = 0; i < 4; ++i)
    t[ty*4 + i][tx] = W[(size_t)(k0 + ty*4 + i) * N + n0 + tx];
  __syncthreads();
#pragma unroll
  for(int i = 0; i < 4; ++i){
    int n = ty*4 + i;
    float v = t[tx][n];
    bf16_t h = (bf16_t)v;
    bf16_t l = (bf16_t)(v - (float)h);
    Th[(size_t)(n0 + n) * K + k0 + tx] = h;
    Tl[(size_t)(n0 + n) * K + k0 + tx] = l;
  }
}

// ---------------- MFMA split-bf16 GEMM (single output; rproj + relation update) ----------------

template<bool RELU_A, bool HAS_BIAS, bool WRITE_BF16, bool SPLITK>
__global__ __launch_bounds__(256) void gemm_mfma_kernel(
    const float* __restrict__ A,
    const bf16_t* __restrict__ Bt_hi, const bf16_t* __restrict__ Bt_lo,
    const float* __restrict__ bias, float* __restrict__ C, bf16_t* __restrict__ Cb,
    int M, int N, int K){
  constexpr int LDK = 40;
  __shared__ bf16_t Ah[128 * LDK];
  __shared__ bf16_t Al[128 * LDK];
  __shared__ bf16_t Bh[128 * LDK];
  __shared__ bf16_t Bl[128 * LDK];

  const int tid  = threadIdx.x;
  const int lane = tid & 63;
  const int wid  = tid >> 6;
  const int wm = wid >> 1, wn = wid & 1;
  const int row0 = blockIdx.y * 128, col0 = blockIdx.x * 128;
  const int l15 = lane & 15;
  const int kb  = (lane >> 4) * 8;

  f32x4 acc[4][4];
#pragma unroll
  for(int m = 0; m < 4; ++m)
#pragma unroll
    for(int n = 0; n < 4; ++n) acc[m][n] = (f32x4){0.f, 0.f, 0.f, 0.f};

  int kbeg = 0, kend = K;
  if(SPLITK){ kbeg = blockIdx.z * 128; kend = kbeg + 128; }

  for(int k0 = kbeg; k0 < kend; k0 += 32){
    __syncthreads();
#pragma unroll
    for(int i = 0; i < 4; ++i){
      int f = tid + i * 256;
      int r = f >> 3, kq = f & 7;
      float4 v = make_float4(0.f, 0.f, 0.f, 0.f);
      if(row0 + r < M) v = *(const float4*)(A + (size_t)(row0 + r) * K + k0 + kq * 4);
      if(RELU_A){ v.x = fmaxf(v.x, 0.f); v.y = fmaxf(v.y, 0.f); v.z = fmaxf(v.z, 0.f); v.w = fmaxf(v.w, 0.f); }
      bf16_t h0 = (bf16_t)v.x, h1 = (bf16_t)v.y, h2 = (bf16_t)v.z, h3 = (bf16_t)v.w;
      bf16x4 hv = (bf16x4){h0, h1, h2, h3};
      bf16x4 lv = (bf16x4){(bf16_t)(v.x - (float)h0), (bf16_t)(v.y - (float)h1),
                           (bf16_t)(v.z - (float)h2), (bf16_t)(v.w - (float)h3)};
      *(bf16x4*)&Ah[r * LDK + kq * 4] = hv;
      *(bf16x4*)&Al[r * LDK + kq * 4] = lv;
    }
#pragma unroll
    for(int i = 0; i < 2; ++i){
      int f = tid + i * 256;
      int n = f >> 2, kq = f & 3;
      *(bf16x8*)&Bh[n * LDK + kq * 8] = *(const bf16x8*)(Bt_hi + (size_t)(col0 + n) * K + k0 + kq * 8);
      *(bf16x8*)&Bl[n * LDK + kq * 8] = *(const bf16x8*)(Bt_lo + (size_t)(col0 + n) * K + k0 + kq * 8);
    }
    __syncthreads();

    bf16x8 ah[4], al[4], bh[4], bl[4];
#pragma unroll
    for(int m = 0; m < 4; ++m){
      int r = wm * 64 + m * 16 + l15;
      ah[m] = *(bf16x8*)&Ah[r * LDK + kb];
      al[m] = *(bf16x8*)&Al[r * LDK + kb];
    }
#pragma unroll
    for(int n = 0; n < 4; ++n){
      int c = wn * 64 + n * 16 + l15;
      bh[n] = *(bf16x8*)&Bh[c * LDK + kb];
      bl[n] = *(bf16x8*)&Bl[c * LDK + kb];
    }
#pragma unroll
    for(int m = 0; m < 4; ++m)
#pragma unroll
      for(int n = 0; n < 4; ++n){
        acc[m][n] = __builtin_amdgcn_mfma_f32_16x16x32_bf16(ah[m], bh[n], acc[m][n], 0, 0, 0);
        acc[m][n] = __builtin_amdgcn_mfma_f32_16x16x32_bf16(ah[m], bl[n], acc[m][n], 0, 0, 0);
        acc[m][n] = __builtin_amdgcn_mfma_f32_16x16x32_bf16(al[m], bh[n], acc[m][n], 0, 0, 0);
      }
  }

  // D layout: row = (lane>>4)*4 + reg, col = lane&15
#pragma unroll
  for(int n = 0; n < 4; ++n){
    int col = col0 + wn * 64 + n * 16 + l15;
    float bv = HAS_BIAS ? bias[col] : 0.f;
#pragma unroll
    for(int m = 0; m < 4; ++m){
      int rbase = row0 + wm * 64 + m * 16 + (lane >> 4) * 4;
#pragma unroll
      for(int r = 0; r < 4; ++r){
        if(rbase + r < M){
          size_t idx = (size_t)(rbase + r) * N + col;
          if(SPLITK){
            atomicAdd(&C[idx], acc[m][n][r]);
          } else {
            float val = acc[m][n][r] + bv;
            C[idx] = val;
            if(WRITE_BF16) Cb[idx] = (bf16_t)val;
          }
        }
      }
    }
  }
}

// ---------------- MFMA dual GEMM: bf16 xl,xr from one A staging ----------------
// Writes ONLY bf16 outputs (write-BW was the R5 limiter). LDS-repack epilogue for
// coalesced 16B stores. XCD-bijective block swizzle (grid must satisfy nwg%8==0).

__global__ __launch_bounds__(256, 2) void gemm_dual_mfma_kernel(
    const float* __restrict__ A,
    const bf16_t* __restrict__ BLh, const bf16_t* __restrict__ BLl,
    const bf16_t* __restrict__ BRh, const bf16_t* __restrict__ BRl,
    const float* __restrict__ biasL, const float* __restrict__ biasR,
    bf16_t* __restrict__ CLb, bf16_t* __restrict__ CRb,
    int M, int Nc, int K){
  constexpr int LDK = 40;
  __shared__ char smem_raw[61440];
  bf16_t* Ah  = (bf16_t*)smem_raw;                    // 10240 B
  bf16_t* Al  = (bf16_t*)(smem_raw + 10240);          // 10240 B
  bf16_t* Bh0 = (bf16_t*)(smem_raw + 20480);          // 10240 B
  bf16_t* Bh1 = (bf16_t*)(smem_raw + 30720);
  bf16_t* Bl0 = (bf16_t*)(smem_raw + 40960);
  bf16_t* Bl1 = (bf16_t*)(smem_raw + 51200);

  const int tid  = threadIdx.x;
  const int lane = tid & 63;
  const int wid  = tid >> 6;
  const int wm = wid >> 1, wn = wid & 1;

  // XCD-aware bijective swizzle: consecutive work-ids (sharing a row panel) on one XCD
  int nwg = gridDim.x * gridDim.y;
  int lin = blockIdx.y * gridDim.x + blockIdx.x;
  int w = ((nwg & 7) == 0) ? ((lin & 7) * (nwg >> 3) + (lin >> 3)) : lin;
  const int row0 = (w / gridDim.x) * 128, col0 = (w % gridDim.x) * 128;

  const int l15 = lane & 15;
  const int kb  = (lane >> 4) * 8;

  f32x4 acc[2][4][4];
#pragma unroll
  for(int s = 0; s < 2; ++s)
#pragma unroll
    for(int m = 0; m < 4; ++m)
#pragma unroll
      for(int n = 0; n < 4; ++n) acc[s][m][n] = (f32x4){0.f, 0.f, 0.f, 0.f};

  for(int k0 = 0; k0 < K; k0 += 32){
    __syncthreads();
#pragma unroll
    for(int i = 0; i < 4; ++i){
      int f = tid + i * 256;
      int r = f >> 3, kq = f & 7;
      float4 v = make_float4(0.f, 0.f, 0.f, 0.f);
      if(row0 + r < M) v = *(const float4*)(A + (size_t)(row0 + r) * K + k0 + kq * 4);
      bf16_t h0 = (bf16_t)v.x, h1 = (bf16_t)v.y, h2 = (bf16_t)v.z, h3 = (bf16_t)v.w;
      bf16x4 hv = (bf16x4){h0, h1, h2, h3};
      bf16x4 lv = (bf16x4){(bf16_t)(v.x - (float)h0), (bf16_t)(v.y - (float)h1),
                           (bf16_t)(v.z - (float)h2), (bf16_t)(v.w - (float)h3)};
      *(bf16x4*)&Ah[r * LDK + kq * 4] = hv;
      *(bf16x4*)&Al[r * LDK + kq * 4] = lv;
    }
#pragma unroll
    for(int i = 0; i < 2; ++i){
      int f = tid + i * 256;
      int n = f >> 2, kq = f & 3;
      size_t g = (size_t)(col0 + n) * K + k0 + kq * 8;
      int lo = n * LDK + kq * 8;
      *(bf16x8*)&Bh0[lo] = *(const bf16x8*)(BLh + g);
      *(bf16x8*)&Bl0[lo] = *(const bf16x8*)(BLl + g);
      *(bf16x8*)&Bh1[lo] = *(const bf16x8*)(BRh + g);
      *(bf16x8*)&Bl1[lo] = *(const bf16x8*)(BRl + g);
    }
    __syncthreads();

    bf16x8 ah[4], al[4];
#pragma unroll
    for(int m = 0; m < 4; ++m){
      int r = wm * 64 + m * 16 + l15;
      ah[m] = *(bf16x8*)&Ah[r * LDK + kb];
      al[m] = *(bf16x8*)&Al[r * LDK + kb];
    }
    {
      bf16x8 bh[4], bl[4];
#pragma unroll
      for(int n = 0; n < 4; ++n){
        int c = wn * 64 + n * 16 + l15;
        bh[n] = *(bf16x8*)&Bh0[c * LDK + kb];
        bl[n] = *(bf16x8*)&Bl0[c * LDK + kb];
      }
#pragma unroll
      for(int m = 0; m < 4; ++m)
#pragma unroll
        for(int n = 0; n < 4; ++n){
          acc[0][m][n] = __builtin_amdgcn_mfma_f32_16x16x32_bf16(ah[m], bh[n], acc[0][m][n], 0, 0, 0);
          acc[0][m][n] = __builtin_amdgcn_mfma_f32_16x16x32_bf16(ah[m], bl[n], acc[0][m][n], 0, 0, 0);
          acc[0][m][n] = __builtin_amdgcn_mfma_f32_16x16x32_bf16(al[m], bh[n], acc[0][m][n], 0, 0, 0);
        }
    }
    {
      bf16x8 bh[4], bl[4];
#pragma unroll
      for(int n = 0; n < 4; ++n){
        int c = wn * 64 + n * 16 + l15;
        bh[n] = *(bf16x8*)&Bh1[c * LDK + kb];
        bl[n] = *(bf16x8*)&Bl1[c * LDK + kb];
      }
#pragma unroll
      for(int m = 0; m < 4; ++m)
#pragma unroll
        for(int n = 0; n < 4; ++n){
          acc[1][m][n] = __builtin_amdgcn_mfma_f32_16x16x32_bf16(ah[m], bh[n], acc[1][m][n], 0, 0, 0);
          acc[1][m][n] = __builtin_amdgcn_mfma_f32_16x16x32_bf16(ah[m], bl[n], acc[1][m][n], 0, 0, 0);
          acc[1][m][n] = __builtin_amdgcn_mfma_f32_16x16x32_bf16(al[m], bh[n], acc[1][m][n], 0, 0, 0);
        }
    }
  }

  // epilogue: bias + bf16 convert into LDS tile, then coalesced 16B stores
  bf16_t* tile = (bf16_t*)smem_raw;   // 128x128 bf16 = 32768 B (reuses staging LDS)
#pragma unroll
  for(int s = 0; s < 2; ++s){
    __syncthreads();
#pragma unroll
    for(int n = 0; n < 4; ++n){
      int col = wn * 64 + n * 16 + l15;
      float bv = (s == 0 ? biasL : biasR)[col0 + col];
#pragma unroll
      for(int m = 0; m < 4; ++m){
        int rb = wm * 64 + m * 16 + (lane >> 4) * 4;
#pragma unroll
        for(int r = 0; r < 4; ++r)
          tile[(rb + r) * 128 + col] = (bf16_t)(acc[s][m][n][r] + bv);
      }
    }
    __syncthreads();
    bf16_t* dst = (s == 0) ? CLb : CRb;
#pragma unroll
    for(int i = 0; i < 8; ++i){
      int ei = i * 2048 + tid * 8;
      int rr = ei >> 7, cc = ei & 127;
      if(row0 + rr < M)
        *(bf16x8*)(dst + (size_t)(row0 + rr) * Nc + col0 + cc) = *(bf16x8*)&tile[rr * 128 + cc];
    }
  }
}

// ---------------- single-pass fused node kernel: one wave per node ----------------
// Online softmax; all row operands bf16 (xr rounding is common-mode across a node's
// edges -> cancels in softmax). 2-edge unroll with merged rescale for MLP.
// No lambdas / address-taken state (R4 scratch-spill lesson).

__global__ __launch_bounds__(256) void node_fused_kernel(
    const bf16_t* __restrict__ xlb, const bf16_t* __restrict__ xrb,
    const bf16_t* __restrict__ rpb,
    const int* __restrict__ offs, const int* __restrict__ srcs, const int* __restrict__ rels,
    const float* __restrict__ att, const float* __restrict__ bias,
    float* __restrict__ xout, int N){
  int node = (int)((blockIdx.x * blockDim.x + threadIdx.x) >> 6);
  int lane = threadIdx.x & 63;
  if(node >= N) return;
  int beg = offs[node], end = offs[node + 1];
  float inv = 1.0f / fmaxf((float)(end - beg), 1.0f);

  const int o0 = lane * 8, o1 = (64 + lane) * 8;
  const int c0 = (lane & 15) * 8;
  f32x8 av0 = *(const f32x8*)(att + (lane >> 4) * 128 + c0);
  f32x8 av1 = *(const f32x8*)(att + (4 + (lane >> 4)) * 128 + c0);
  const bf16_t* xrn = xrb + (size_t)node * 1024;
  bf16x8 xrv0 = *(const bf16x8*)(xrn + o0);
  bf16x8 xrv1 = *(const bf16x8*)(xrn + o1);
  f32x8 xr0, xr1;
#pragma unroll
  for(int i = 0; i < 8; ++i){ xr0[i] = (float)xrv0[i]; xr1[i] = (float)xrv1[i]; }

  f32x8 lac0, lac1, num0, num1;
#pragma unroll
  for(int i = 0; i < 8; ++i){ lac0[i] = 0.f; lac1[i] = 0.f; num0[i] = 0.f; num1[i] = 0.f; }
  float m0 = -INFINITY, m1 = -INFINITY, den0 = 0.f, den1 = 0.f;

  int p = beg;
  for(; p + 1 < end; p += 2){
    int sA = srcs[p],     rA = rels[p];
    int sB = srcs[p + 1], rB = rels[p + 1];
    const bf16_t* xsA = xlb + (size_t)sA * 1024;
    const bf16_t* rpA = rpb + (size_t)rA * 1024;
    const bf16_t* xsB = xlb + (size_t)sB * 1024;
    const bf16_t* rpB = rpb + (size_t)rB * 1024;
    bf16x8 aA0 = *(const bf16x8*)(xsA + o0), aA1 = *(const bf16x8*)(xsA + o1);
    bf16x8 bA0 = *(const bf16x8*)(rpA + o0), bA1 = *(const bf16x8*)(rpA + o1);
    bf16x8 aB0 = *(const bf16x8*)(xsB + o0), aB1 = *(const bf16x8*)(xsB + o1);
    bf16x8 bB0 = *(const bf16x8*)(rpB + o0), bB1 = *(const bf16x8*)(rpB + o1);
    f32x8 fA0, fA1, fB0, fB1;
    float rA0 = 0.f, rA1 = 0.f, rB0 = 0.f, rB1 = 0.f;
#pragma unroll
    for(int i = 0; i < 8; ++i){
      float v;
      v = (float)bA0[i]; lac0[i] += v; fA0[i] = (float)aA0[i];
      rA0 += leaky(fA0[i] + xr0[i] + v) * av0[i];
      v = (float)bA1[i]; lac1[i] += v; fA1[i] = (float)aA1[i];
      rA1 += leaky(fA1[i] + xr1[i] + v) * av1[i];
      v = (float)bB0[i]; lac0[i] += v; fB0[i] = (float)aB0[i];
      rB0 += leaky(fB0[i] + xr0[i] + v) * av0[i];
      v = (float)bB1[i]; lac1[i] += v; fB1[i] = (float)aB1[i];
      rB1 += leaky(fB1[i] + xr1[i] + v) * av1[i];
    }
#pragma unroll
    for(int o = 8; o >= 1; o >>= 1){
      rA0 += __shfl_xor(rA0, o); rA1 += __shfl_xor(rA1, o);
      rB0 += __shfl_xor(rB0, o); rB1 += __shfl_xor(rB1, o);
    }
    // merged online update, head-group 0
    {
      float nm = fmaxf(m0, fmaxf(rA0, rB0));
      float sc = __expf(m0 - nm), wa = __expf(rA0 - nm), wb = __expf(rB0 - nm);
      den0 = den0 * sc + wa + wb;
#pragma unroll
      for(int i = 0; i < 8; ++i) num0[i] = num0[i] * sc + wa * fA0[i] + wb * fB0[i];
      m0 = nm;
    }
    // merged online update, head-group 1
    {
      float nm = fmaxf(m1, fmaxf(rA1, rB1));
      float sc = __expf(m1 - nm), wa = __expf(rA1 - nm), wb = __expf(rB1 - nm);
      den1 = den1 * sc + wa + wb;
#pragma unroll
      for(int i = 0; i < 8; ++i) num1[i] = num1[i] * sc + wa * fA1[i] + wb * fB1[i];
      m1 = nm;
    }
  }
  if(p < end){
    int sA = srcs[p], rA = rels[p];
    const bf16_t* xsA = xlb + (size_t)sA * 1024;
    const bf16_t* rpA = rpb + (size_t)rA * 1024;
    bf16x8 aA0 = *(const bf16x8*)(xsA + o0), aA1 = *(const bf16x8*)(xsA + o1);
    bf16x8 bA0 = *(const bf16x8*)(rpA + o0), bA1 = *(const bf16x8*)(rpA + o1);
    f32x8 fA0, fA1;
    float rA0 = 0.f, rA1 = 0.f;
#pragma unroll
    for(int i = 0; i < 8; ++i){
      float v;
      v = (float)bA0[i]; lac0[i] += v; fA0[i] = (float)aA0[i];
      rA0 += leaky(fA0[i] + xr0[i] + v) * av0[i];
      v = (float)bA1[i]; lac1[i] += v; fA1[i] = (float)aA1[i];
      rA1 += leaky(fA1[i] + xr1[i] + v) * av1[i];
    }
#pragma unroll
    for(int o = 8; o >= 1; o >>= 1){
      rA0 += __shfl_xor(rA0, o); rA1 += __shfl_xor(rA1, o);
    }
    {
      float nm = fmaxf(m0, rA0);
      float sc = __expf(m0 - nm), wa = __expf(rA0 - nm);
      den0 = den0 * sc + wa;
#pragma unroll
      for(int i = 0; i < 8; ++i) num0[i] = num0[i] * sc + wa * fA0[i];
      m0 = nm;
    }
    {
      float nm = fmaxf(m1, rA1);
      float sc = __expf(m1 - nm), wa = __expf(rA1 - nm);
      den1 = den1 * sc + wa;
#pragma unroll
      for(int i = 0; i < 8; ++i) num1[i] = num1[i] * sc + wa * fA1[i];
      m1 = nm;
    }
  }

  // self loop: edge_attr = mean of incoming rproj; self message = own xl row (bf16)
  const bf16_t* xln = xlb + (size_t)node * 1024;
  bf16x8 xlv0 = *(const bf16x8*)(xln + o0);
  bf16x8 xlv1 = *(const bf16x8*)(xln + o1);
  f32x8 xl0, xl1;
#pragma unroll
  for(int i = 0; i < 8; ++i){ xl0[i] = (float)xlv0[i]; xl1[i] = (float)xlv1[i]; }
  float s0 = 0.f, s1 = 0.f;
#pragma unroll
  for(int i = 0; i < 8; ++i){
    s0 += leaky(xl0[i] + xr0[i] + lac0[i] * inv) * av0[i];
    s1 += leaky(xl1[i] + xr1[i] + lac1[i] * inv) * av1[i];
  }
#pragma unroll
  for(int o = 8; o >= 1; o >>= 1){
    s0 += __shfl_xor(s0, o); s1 += __shfl_xor(s1, o);
  }
  {
    float nm = fmaxf(m0, s0);
    float sc = __expf(m0 - nm), w = __expf(s0 - nm);
    den0 = den0 * sc + w;
#pragma unroll
    for(int i = 0; i < 8; ++i) num0[i] = num0[i] * sc + w * xl0[i];
    m0 = nm;
  }
  {
    float nm = fmaxf(m1, s1);
    float sc = __expf(m1 - nm), w = __expf(s1 - nm);
    den1 = den1 * sc + w;
#pragma unroll
    for(int i = 0; i < 8; ++i) num1[i] = num1[i] * sc + w * xl1[i];
    m1 = nm;
  }

  // per-head normalize, sum 8 heads, mean + bias
  f32x8 t;
  float d0 = 1.0f / den0, d1 = 1.0f / den1;
#pragma unroll
  for(int i = 0; i < 8; ++i) t[i] = num0[i] * d0 + num1[i] * d1;
#pragma unroll
  for(int i = 0; i < 8; ++i) t[i] += __shfl_xor(t[i], 16);
#pragma unroll
  for(int i = 0; i < 8; ++i) t[i] += __shfl_xor(t[i], 32);

  if(lane < 16){
    const float* bp = bias + lane * 8;
    float* op = xout + (size_t)node * 128 + lane * 8;
    float4 q0 = make_float4(t[0]*0.125f + bp[0], t[1]*0.125f + bp[1],
                            t[2]*0.125f + bp[2], t[3]*0.125f + bp[3]);
    float4 q1 = make_float4(t[4]*0.125f + bp[4], t[5]*0.125f + bp[5],
                            t[6]*0.125f + bp[6], t[7]*0.125f + bp[7]);
    *(float4*)op = q0;
    *(float4*)(op + 4) = q1;
  }
}

// ---------------- launch ----------------

extern "C" void kernel_launch(void* const* d_in, const int* in_sizes, int n_in,
                              void* d_out, int out_size, void* d_ws, size_t ws_size,
                              hipStream_t stream){
  const float* x0   = (const float*)d_in[0];
  const int*   ei   = (const int*)d_in[1];
  const float* rel0 = (const float*)d_in[2];
  const int*   ridx = (const int*)d_in[3];
  const float* Wl   = (const float*)d_in[4];
  const float* bl   = (const float*)d_in[5];
  const float* Wr   = (const float*)d_in[6];
  const float* br   = (const float*)d_in[7];
  const float* We   = (const float*)d_in[8];
  const float* att  = (const float*)d_in[9];
  const float* bias = (const float*)d_in[10];
  const float* Wb   = (const float*)d_in[11];
  const float* bb   = (const float*)d_in[12];

  const int D = 128, HC = 1024;
  const int N = in_sizes[0] / D;
  const int E = in_sizes[1] / 2;
  const int R = in_sizes[2] / D;
  const int WSZ = D * HC;

  const int* src = ei;
  const int* dst = ei + E;

  char* ws = (char*)d_ws;
  size_t off = 0;
  auto alloc = [&](size_t bytes) -> void* {
    void* p = ws + off;
    off += (bytes + 255) & ~(size_t)255;
    return p;
  };
  float*  rproj  = (float*)alloc((size_t)R * HC * 4);
  bf16_t* xlb    = (bf16_t*)alloc((size_t)N * HC * 2);
  bf16_t* xrb    = (bf16_t*)alloc((size_t)N * HC * 2);
  bf16_t* rpb    = (bf16_t*)alloc((size_t)R * HC * 2);
  float*  xbufA  = (float*)alloc((size_t)N * D * 4);
  float*  xbufB  = (float*)alloc((size_t)N * D * 4);
  float*  rbufA  = (float*)alloc((size_t)R * D * 4);
  float*  rbufB  = (float*)alloc((size_t)R * D * 4);
  int* deg    = (int*)alloc((size_t)N * 4);
  int* offs   = (int*)alloc((size_t)(N + 1) * 4);
  int* cursor = (int*)alloc((size_t)N * 4);
  int* srcs   = (int*)alloc((size_t)E * 4);
  int* rels   = (int*)alloc((size_t)E * 4);
  bf16_t* tWl_h = (bf16_t*)alloc((size_t)N_LAYERS * WSZ * 2);
  bf16_t* tWl_l = (bf16_t*)alloc((size_t)N_LAYERS * WSZ * 2);
  bf16_t* tWr_h = (bf16_t*)alloc((size_t)N_LAYERS * WSZ * 2);
  bf16_t* tWr_l = (bf16_t*)alloc((size_t)N_LAYERS * WSZ * 2);
  bf16_t* tWe_h = (bf16_t*)alloc((size_t)N_LAYERS * WSZ * 2);
  bf16_t* tWe_l = (bf16_t*)alloc((size_t)N_LAYERS * WSZ * 2);
  bf16_t* tWb_h = (bf16_t*)alloc((size_t)N_LAYERS * WSZ * 2);
  bf16_t* tWb_l = (bf16_t*)alloc((size_t)N_LAYERS * WSZ * 2);
  float* xbuf[2] = {xbufA, xbufB};
  float* rbuf[2] = {rbufA, rbufB};

  float* out_x = (float*)d_out;
  float* out_r = (float*)d_out + (size_t)N * D;

  // CSR build (once; edge structure is layer-invariant)
  fill_int_kernel<<<(N + 255) / 256, 256, 0, stream>>>(deg, 0, N);
  fill_int_kernel<<<(N + 255) / 256, 256, 0, stream>>>(cursor, 0, N);
  hist_kernel<<<(E + 255) / 256, 256, 0, stream>>>(dst, E, deg);
  scan_kernel<<<1, 256, 0, stream>>>(deg, offs, N);
  scatter_kernel<<<(E + 255) / 256, 256, 0, stream>>>(src, dst, ridx, E, offs, cursor, srcs, rels);

  // weight prep: transpose + hi/lo split (all layers, upfront)
  dim3 tblk(32, 8);
  for(int l = 0; l < N_LAYERS; ++l){
    size_t wo = (size_t)l * WSZ;
    transpose_split_kernel<<<dim3(D/32, HC/32), tblk, 0, stream>>>(Wl + wo, tWl_h + wo, tWl_l + wo, D, HC);
    transpose_split_kernel<<<dim3(D/32, HC/32), tblk, 0, stream>>>(Wr + wo, tWr_h + wo, tWr_l + wo, D, HC);
    transpose_split_kernel<<<dim3(D/32, HC/32), tblk, 0, stream>>>(We + wo, tWe_h + wo, tWe_l + wo, D, HC);
    transpose_split_kernel<<<dim3(HC/32, D/32), tblk, 0, stream>>>(Wb + wo, tWb_h + wo, tWb_l + wo, HC, D);
  }

  for(int l = 0; l < N_LAYERS; ++l){
    const float* xin = (l == 0) ? x0   : xbuf[(l + 1) & 1];
    float*       xo  = (l == N_LAYERS - 1) ? out_x : xbuf[l & 1];
    const float* rin = (l == 0) ? rel0 : rbuf[(l + 1) & 1];
    float*       ro  = (l == N_LAYERS - 1) ? out_r : rbuf[l & 1];
    size_t wo = (size_t)l * WSZ;
    const float* bl_l  = bl + (size_t)l * HC;
    const float* br_l  = br + (size_t)l * HC;
    const float* att_l = att + (size_t)l * 8 * 128;
    const float* bias_l= bias + (size_t)l * D;
    const float* bb_l  = bb + (size_t)l * D;

    // rproj = relations @ We (no bias) + bf16 copy
    gemm_mfma_kernel<false,false,true,false><<<dim3(HC/128, (R+127)/128), 256, 0, stream>>>(
        rin, tWe_h + wo, tWe_l + wo, nullptr, rproj, rpb, R, HC, D);
    // fused xl/xr projection, bf16 outputs only
    gemm_dual_mfma_kernel<<<dim3(HC/128, (N+127)/128), 256, 0, stream>>>(
        xin, tWl_h + wo, tWl_l + wo, tWr_h + wo, tWr_l + wo,
        bl_l, br_l, xlb, xrb, N, HC, D);
    // single-pass fused node kernel
    node_fused_kernel<<<(N * 64 + 255) / 256, 256, 0, stream>>>(
        xlb, xrb, rpb, offs, srcs, rels, att_l, bias_l, xo, N);
    // relation update: ro = relu(rproj) @ Wb + bb, split-K over 8 slices
    fill_bias_kernel<<<(R * 128 + 255) / 256, 256, 0, stream>>>(ro, bb_l, R);
    gemm_mfma_kernel<true,false,false,true><<<dim3(D/128, (R+127)/128, 8), 256, 0, stream>>>(
        rproj, tWb_h + wo, tWb_l + wo, nullptr, ro, nullptr, R, D, HC);
  }
}

// Round 7
// 561.559 us; speedup vs baseline: 1.6551x; 1.0413x over previous
//
#include <hip/hip_runtime.h>
#include <hip/hip_bf16.h>
#include <math.h>

#define NEG_SLOPE 0.2f
#define N_LAYERS 4

typedef __bf16 bf16_t;
typedef __attribute__((ext_vector_type(8))) __bf16 bf16x8;
typedef __attribute__((ext_vector_type(4))) __bf16 bf16x4;
typedef __attribute__((ext_vector_type(4))) float f32x4;
typedef __attribute__((ext_vector_type(8))) float f32x8;

static __device__ __forceinline__ float leaky(float v){ return v > 0.f ? v : NEG_SLOPE * v; }

// ---------------- CSR build + degree sort (edge structure fixed across layers) --------

__global__ void fill_int_kernel(int* __restrict__ p, int v, int n){
  int i = blockIdx.x*blockDim.x + threadIdx.x;
  if(i < n) p[i] = v;
}

__global__ void fill_bias_kernel(float* __restrict__ out, const float* __restrict__ b, int rows){
  int i = blockIdx.x*blockDim.x + threadIdx.x;
  if(i < rows * 128) out[i] = b[i & 127];
}

__global__ void hist_kernel(const int* __restrict__ dst, int E, int* __restrict__ deg){
  int e = blockIdx.x*blockDim.x + threadIdx.x;
  if(e < E) atomicAdd(&deg[dst[e]], 1);
}

// exclusive scan via wave shuffles: offs[0]=0, offs[i+1]=sum(deg[0..i]). One block, 256 thr.
__global__ void scan_kernel(const int* __restrict__ deg, int* __restrict__ offs, int N){
  __shared__ int wsum[4];
  int t = threadIdx.x, lane = t & 63, w = t >> 6;
  int carry = 0;
  for(int base = 0; base < N; base += 256){
    int v = (base + t < N) ? deg[base + t] : 0;
    int s = v;
#pragma unroll
    for(int o = 1; o < 64; o <<= 1){
      int u = __shfl_up(s, o);
      if(lane >= o) s += u;
    }
    if(lane == 63) wsum[w] = s;
    __syncthreads();
    int woff = 0;
    for(int i = 0; i < w; ++i) woff += wsum[i];
    if(base + t < N) offs[base + t + 1] = carry + woff + s;
    int tot = wsum[0] + wsum[1] + wsum[2] + wsum[3];
    __syncthreads();
    carry += tot;
  }
  if(t == 0) offs[0] = 0;
}

__global__ void scatter_kernel(const int* __restrict__ src, const int* __restrict__ dst,
                               const int* __restrict__ rel, int E,
                               const int* __restrict__ offs, int* __restrict__ cursor,
                               int* __restrict__ srcs, int* __restrict__ rels){
  int e = blockIdx.x*blockDim.x + threadIdx.x;
  if(e < E){
    int d = dst[e];
    int pos = offs[d] + atomicAdd(&cursor[d], 1);
    srcs[pos] = src[e];
    rels[pos] = rel[e];
  }
}

// degree-descending counting sort (256 buckets, clamped)
__global__ void deg_hist_kernel(const int* __restrict__ offs, int N, int* __restrict__ cnt){
  int i = blockIdx.x*blockDim.x + threadIdx.x;
  if(i < N){
    int d = offs[i+1] - offs[i]; if(d > 255) d = 255;
    atomicAdd(&cnt[d], 1);
  }
}

__global__ void deg_offset_kernel(const int* __restrict__ cnt, int* __restrict__ boff){
  __shared__ int c[256];
  int d = threadIdx.x;
  c[d] = cnt[d];
  __syncthreads();
  int s = 0;
  for(int k = d + 1; k < 256; ++k) s += c[k];
  boff[d] = s;
}

__global__ void deg_scatter_kernel(const int* __restrict__ offs, int N,
                                   const int* __restrict__ boff, int* __restrict__ cur,
                                   int* __restrict__ order){
  int i = blockIdx.x*blockDim.x + threadIdx.x;
  if(i < N){
    int d = offs[i+1] - offs[i]; if(d > 255) d = 255;
    int pos = boff[d] + atomicAdd(&cur[d], 1);
    order[pos] = i;
  }
}

// ---------------- batched weight transpose + bf16 hi/lo split (all 16 in one dispatch) ----

__global__ void transpose_split_all_kernel(
    const float* __restrict__ Wl, const float* __restrict__ Wr,
    const float* __restrict__ We, const float* __restrict__ Wb,
    bf16_t* __restrict__ tWlh, bf16_t* __restrict__ tWll,
    bf16_t* __restrict__ tWrh, bf16_t* __restrict__ tWrl,
    bf16_t* __restrict__ tWeh, bf16_t* __restrict__ tWel,
    bf16_t* __restrict__ tWbh, bf16_t* __restrict__ tWbl){
  __shared__ float t[32][33];
  const int z = blockIdx.z, type = z >> 2, layer = z & 3;
  const int K  = (type < 3) ? 128 : 1024;
  const int Nn = (type < 3) ? 1024 : 128;
  const float* W; bf16_t* Th; bf16_t* Tl;
  if(type == 0){ W = Wl; Th = tWlh; Tl = tWll; }
  else if(type == 1){ W = Wr; Th = tWrh; Tl = tWrl; }
  else if(type == 2){ W = We; Th = tWeh; Tl = tWel; }
  else { W = Wb; Th = tWbh; Tl = tWbl; }
  size_t wo = (size_t)layer * 131072;
  W += wo; Th += wo; Tl += wo;
  const int nbx = K / 32;
  const int bx = blockIdx.x % nbx, by = blockIdx.x / nbx;
  const int k0 = bx * 32, n0 = by * 32;
  const int tx = threadIdx.x, ty = threadIdx.y;
#pragma unroll
  for(int i = 0; i < 4; ++i)
    t[ty*4 + i][tx] = W[(size_t)(k0 + ty*4 + i) * Nn + n0 + tx];
  __syncthreads();
#pragma unroll
  for(int i = 0; i < 4; ++i){
    int n = ty*4 + i;
    float v = t[tx][n];
    bf16_t h = (bf16_t)v;
    bf16_t l = (bf16_t)(v - (float)h);
    Th[(size_t)(n0 + n) * K + k0 + tx] = h;
    Tl[(size_t)(n0 + n) * K + k0 + tx] = l;
  }
}

// ---------------- MFMA split-bf16 GEMM (single output; rproj + relation update) ----------------

template<bool RELU_A, bool HAS_BIAS, bool WRITE_BF16, bool SPLITK>
__global__ __launch_bounds__(256) void gemm_mfma_kernel(
    const float* __restrict__ A,
    const bf16_t* __restrict__ Bt_hi, const bf16_t* __restrict__ Bt_lo,
    const float* __restrict__ bias, float* __restrict__ C, bf16_t* __restrict__ Cb,
    int M, int N, int K){
  constexpr int LDK = 40;
  __shared__ bf16_t Ah[128 * LDK];
  __shared__ bf16_t Al[128 * LDK];
  __shared__ bf16_t Bh[128 * LDK];
  __shared__ bf16_t Bl[128 * LDK];

  const int tid  = threadIdx.x;
  const int lane = tid & 63;
  const int wid  = tid >> 6;
  const int wm = wid >> 1, wn = wid & 1;
  const int row0 = blockIdx.y * 128, col0 = blockIdx.x * 128;
  const int l15 = lane & 15;
  const int kb  = (lane >> 4) * 8;

  f32x4 acc[4][4];
#pragma unroll
  for(int m = 0; m < 4; ++m)
#pragma unroll
    for(int n = 0; n < 4; ++n) acc[m][n] = (f32x4){0.f, 0.f, 0.f, 0.f};

  int kbeg = 0, kend = K;
  if(SPLITK){ kbeg = blockIdx.z * 128; kend = kbeg + 128; }

  for(int k0 = kbeg; k0 < kend; k0 += 32){
    __syncthreads();
#pragma unroll
    for(int i = 0; i < 4; ++i){
      int f = tid + i * 256;
      int r = f >> 3, kq = f & 7;
      float4 v = make_float4(0.f, 0.f, 0.f, 0.f);
      if(row0 + r < M) v = *(const float4*)(A + (size_t)(row0 + r) * K + k0 + kq * 4);
      if(RELU_A){ v.x = fmaxf(v.x, 0.f); v.y = fmaxf(v.y, 0.f); v.z = fmaxf(v.z, 0.f); v.w = fmaxf(v.w, 0.f); }
      bf16_t h0 = (bf16_t)v.x, h1 = (bf16_t)v.y, h2 = (bf16_t)v.z, h3 = (bf16_t)v.w;
      bf16x4 hv = (bf16x4){h0, h1, h2, h3};
      bf16x4 lv = (bf16x4){(bf16_t)(v.x - (float)h0), (bf16_t)(v.y - (float)h1),
                           (bf16_t)(v.z - (float)h2), (bf16_t)(v.w - (float)h3)};
      *(bf16x4*)&Ah[r * LDK + kq * 4] = hv;
      *(bf16x4*)&Al[r * LDK + kq * 4] = lv;
    }
#pragma unroll
    for(int i = 0; i < 2; ++i){
      int f = tid + i * 256;
      int n = f >> 2, kq = f & 3;
      *(bf16x8*)&Bh[n * LDK + kq * 8] = *(const bf16x8*)(Bt_hi + (size_t)(col0 + n) * K + k0 + kq * 8);
      *(bf16x8*)&Bl[n * LDK + kq * 8] = *(const bf16x8*)(Bt_lo + (size_t)(col0 + n) * K + k0 + kq * 8);
    }
    __syncthreads();

    bf16x8 ah[4], al[4], bh[4], bl[4];
#pragma unroll
    for(int m = 0; m < 4; ++m){
      int r = wm * 64 + m * 16 + l15;
      ah[m] = *(bf16x8*)&Ah[r * LDK + kb];
      al[m] = *(bf16x8*)&Al[r * LDK + kb];
    }
#pragma unroll
    for(int n = 0; n < 4; ++n){
      int c = wn * 64 + n * 16 + l15;
      bh[n] = *(bf16x8*)&Bh[c * LDK + kb];
      bl[n] = *(bf16x8*)&Bl[c * LDK + kb];
    }
#pragma unroll
    for(int m = 0; m < 4; ++m)
#pragma unroll
      for(int n = 0; n < 4; ++n){
        acc[m][n] = __builtin_amdgcn_mfma_f32_16x16x32_bf16(ah[m], bh[n], acc[m][n], 0, 0, 0);
        acc[m][n] = __builtin_amdgcn_mfma_f32_16x16x32_bf16(ah[m], bl[n], acc[m][n], 0, 0, 0);
        acc[m][n] = __builtin_amdgcn_mfma_f32_16x16x32_bf16(al[m], bh[n], acc[m][n], 0, 0, 0);
      }
  }

  // D layout: row = (lane>>4)*4 + reg, col = lane&15
#pragma unroll
  for(int n = 0; n < 4; ++n){
    int col = col0 + wn * 64 + n * 16 + l15;
    float bv = HAS_BIAS ? bias[col] : 0.f;
#pragma unroll
    for(int m = 0; m < 4; ++m){
      int rbase = row0 + wm * 64 + m * 16 + (lane >> 4) * 4;
#pragma unroll
      for(int r = 0; r < 4; ++r){
        if(rbase + r < M){
          size_t idx = (size_t)(rbase + r) * N + col;
          if(SPLITK){
            atomicAdd(&C[idx], acc[m][n][r]);
          } else {
            float val = acc[m][n][r] + bv;
            C[idx] = val;
            if(WRITE_BF16) Cb[idx] = (bf16_t)val;
          }
        }
      }
    }
  }
}

// ---------------- MFMA dual GEMM: bf16 xl,xr from one A staging ----------------

__global__ __launch_bounds__(256, 2) void gemm_dual_mfma_kernel(
    const float* __restrict__ A,
    const bf16_t* __restrict__ BLh, const bf16_t* __restrict__ BLl,
    const bf16_t* __restrict__ BRh, const bf16_t* __restrict__ BRl,
    const float* __restrict__ biasL, const float* __restrict__ biasR,
    bf16_t* __restrict__ CLb, bf16_t* __restrict__ CRb,
    int M, int Nc, int K){
  constexpr int LDK = 40;
  __shared__ char smem_raw[61440];
  bf16_t* Ah  = (bf16_t*)smem_raw;
  bf16_t* Al  = (bf16_t*)(smem_raw + 10240);
  bf16_t* Bh0 = (bf16_t*)(smem_raw + 20480);
  bf16_t* Bh1 = (bf16_t*)(smem_raw + 30720);
  bf16_t* Bl0 = (bf16_t*)(smem_raw + 40960);
  bf16_t* Bl1 = (bf16_t*)(smem_raw + 51200);

  const int tid  = threadIdx.x;
  const int lane = tid & 63;
  const int wid  = tid >> 6;
  const int wm = wid >> 1, wn = wid & 1;

  int nwg = gridDim.x * gridDim.y;
  int lin = blockIdx.y * gridDim.x + blockIdx.x;
  int w = ((nwg & 7) == 0) ? ((lin & 7) * (nwg >> 3) + (lin >> 3)) : lin;
  const int row0 = (w / gridDim.x) * 128, col0 = (w % gridDim.x) * 128;

  const int l15 = lane & 15;
  const int kb  = (lane >> 4) * 8;

  f32x4 acc[2][4][4];
#pragma unroll
  for(int s = 0; s < 2; ++s)
#pragma unroll
    for(int m = 0; m < 4; ++m)
#pragma unroll
      for(int n = 0; n < 4; ++n) acc[s][m][n] = (f32x4){0.f, 0.f, 0.f, 0.f};

  for(int k0 = 0; k0 < K; k0 += 32){
    __syncthreads();
#pragma unroll
    for(int i = 0; i < 4; ++i){
      int f = tid + i * 256;
      int r = f >> 3, kq = f & 7;
      float4 v = make_float4(0.f, 0.f, 0.f, 0.f);
      if(row0 + r < M) v = *(const float4*)(A + (size_t)(row0 + r) * K + k0 + kq * 4);
      bf16_t h0 = (bf16_t)v.x, h1 = (bf16_t)v.y, h2 = (bf16_t)v.z, h3 = (bf16_t)v.w;
      bf16x4 hv = (bf16x4){h0, h1, h2, h3};
      bf16x4 lv = (bf16x4){(bf16_t)(v.x - (float)h0), (bf16_t)(v.y - (float)h1),
                           (bf16_t)(v.z - (float)h2), (bf16_t)(v.w - (float)h3)};
      *(bf16x4*)&Ah[r * LDK + kq * 4] = hv;
      *(bf16x4*)&Al[r * LDK + kq * 4] = lv;
    }
#pragma unroll
    for(int i = 0; i < 2; ++i){
      int f = tid + i * 256;
      int n = f >> 2, kq = f & 3;
      size_t g = (size_t)(col0 + n) * K + k0 + kq * 8;
      int lo = n * LDK + kq * 8;
      *(bf16x8*)&Bh0[lo] = *(const bf16x8*)(BLh + g);
      *(bf16x8*)&Bl0[lo] = *(const bf16x8*)(BLl + g);
      *(bf16x8*)&Bh1[lo] = *(const bf16x8*)(BRh + g);
      *(bf16x8*)&Bl1[lo] = *(const bf16x8*)(BRl + g);
    }
    __syncthreads();

    bf16x8 ah[4], al[4];
#pragma unroll
    for(int m = 0; m < 4; ++m){
      int r = wm * 64 + m * 16 + l15;
      ah[m] = *(bf16x8*)&Ah[r * LDK + kb];
      al[m] = *(bf16x8*)&Al[r * LDK + kb];
    }
    {
      bf16x8 bh[4], bl[4];
#pragma unroll
      for(int n = 0; n < 4; ++n){
        int c = wn * 64 + n * 16 + l15;
        bh[n] = *(bf16x8*)&Bh0[c * LDK + kb];
        bl[n] = *(bf16x8*)&Bl0[c * LDK + kb];
      }
#pragma unroll
      for(int m = 0; m < 4; ++m)
#pragma unroll
        for(int n = 0; n < 4; ++n){
          acc[0][m][n] = __builtin_amdgcn_mfma_f32_16x16x32_bf16(ah[m], bh[n], acc[0][m][n], 0, 0, 0);
          acc[0][m][n] = __builtin_amdgcn_mfma_f32_16x16x32_bf16(ah[m], bl[n], acc[0][m][n], 0, 0, 0);
          acc[0][m][n] = __builtin_amdgcn_mfma_f32_16x16x32_bf16(al[m], bh[n], acc[0][m][n], 0, 0, 0);
        }
    }
    {
      bf16x8 bh[4], bl[4];
#pragma unroll
      for(int n = 0; n < 4; ++n){
        int c = wn * 64 + n * 16 + l15;
        bh[n] = *(bf16x8*)&Bh1[c * LDK + kb];
        bl[n] = *(bf16x8*)&Bl1[c * LDK + kb];
      }
#pragma unroll
      for(int m = 0; m < 4; ++m)
#pragma unroll
        for(int n = 0; n < 4; ++n){
          acc[1][m][n] = __builtin_amdgcn_mfma_f32_16x16x32_bf16(ah[m], bh[n], acc[1][m][n], 0, 0, 0);
          acc[1][m][n] = __builtin_amdgcn_mfma_f32_16x16x32_bf16(ah[m], bl[n], acc[1][m][n], 0, 0, 0);
          acc[1][m][n] = __builtin_amdgcn_mfma_f32_16x16x32_bf16(al[m], bh[n], acc[1][m][n], 0, 0, 0);
        }
    }
  }

  // epilogue: bias + bf16 convert into LDS tile, then coalesced 16B stores
  bf16_t* tile = (bf16_t*)smem_raw;
#pragma unroll
  for(int s = 0; s < 2; ++s){
    __syncthreads();
#pragma unroll
    for(int n = 0; n < 4; ++n){
      int col = wn * 64 + n * 16 + l15;
      float bv = (s == 0 ? biasL : biasR)[col0 + col];
#pragma unroll
      for(int m = 0; m < 4; ++m){
        int rb = wm * 64 + m * 16 + (lane >> 4) * 4;
#pragma unroll
        for(int r = 0; r < 4; ++r)
          tile[(rb + r) * 128 + col] = (bf16_t)(acc[s][m][n][r] + bv);
      }
    }
    __syncthreads();
    bf16_t* dst = (s == 0) ? CLb : CRb;
#pragma unroll
    for(int i = 0; i < 8; ++i){
      int ei = i * 2048 + tid * 8;
      int rr = ei >> 7, cc = ei & 127;
      if(row0 + rr < M)
        *(bf16x8*)(dst + (size_t)(row0 + rr) * Nc + col0 + cc) = *(bf16x8*)&tile[rr * 128 + cc];
    }
  }
}

// ---------------- fused node kernel: TWO waves per node (one per 4-head half) ----------
// Online softmax, 4-edge unroll w/ merged rescale, degree-sorted node order,
// LDS combine of the two halves. No lambdas / address-taken state.

__global__ __launch_bounds__(256) void node_fused_kernel(
    const bf16_t* __restrict__ xlb, const bf16_t* __restrict__ xrb,
    const bf16_t* __restrict__ rpb,
    const int* __restrict__ offs, const int* __restrict__ srcs, const int* __restrict__ rels,
    const int* __restrict__ order,
    const float* __restrict__ att, const float* __restrict__ bias,
    float* __restrict__ xout, int N){
  __shared__ float tsh[2][128];
  const int wid  = threadIdx.x >> 6;
  const int lane = threadIdx.x & 63;
  const int nib  = wid >> 1;                    // node-in-block (0/1)
  const int half = wid & 1;                     // head-half (0: h0-3, 1: h4-7)
  const int slot = blockIdx.x * 2 + nib;
  const bool active = slot < N;
  const int node = active ? order[slot] : 0;
  int beg = 0, end = 0;
  if(active){ beg = offs[node]; end = offs[node + 1]; }
  const float inv = 1.0f / fmaxf((float)(end - beg), 1.0f);

  const int o  = (half * 64 + lane) * 8;        // elem offset in 1024-elem row
  const int c0 = (lane & 15) * 8;
  const int h  = half * 4 + (lane >> 4);
  f32x8 av = *(const f32x8*)(att + h * 128 + c0);
  bf16x8 xrv = *(const bf16x8*)(xrb + (size_t)node * 1024 + o);
  f32x8 xr;
#pragma unroll
  for(int i = 0; i < 8; ++i) xr[i] = (float)xrv[i];

  f32x8 lac, num;
#pragma unroll
  for(int i = 0; i < 8; ++i){ lac[i] = 0.f; num[i] = 0.f; }
  float m = -INFINITY, den = 0.f;

  int p = beg;
  for(; p + 3 < end; p += 4){
    int s0 = srcs[p],   r0 = rels[p];
    int s1 = srcs[p+1], r1 = rels[p+1];
    int s2 = srcs[p+2], r2 = rels[p+2];
    int s3 = srcs[p+3], r3 = rels[p+3];
    bf16x8 a0 = *(const bf16x8*)(xlb + (size_t)s0 * 1024 + o);
    bf16x8 b0 = *(const bf16x8*)(rpb + (size_t)r0 * 1024 + o);
    bf16x8 a1 = *(const bf16x8*)(xlb + (size_t)s1 * 1024 + o);
    bf16x8 b1 = *(const bf16x8*)(rpb + (size_t)r1 * 1024 + o);
    bf16x8 a2 = *(const bf16x8*)(xlb + (size_t)s2 * 1024 + o);
    bf16x8 b2 = *(const bf16x8*)(rpb + (size_t)r2 * 1024 + o);
    bf16x8 a3 = *(const bf16x8*)(xlb + (size_t)s3 * 1024 + o);
    bf16x8 b3 = *(const bf16x8*)(rpb + (size_t)r3 * 1024 + o);
    float l0 = 0.f, l1 = 0.f, l2 = 0.f, l3 = 0.f;
#pragma unroll
    for(int i = 0; i < 8; ++i){
      float v;
      v = (float)b0[i]; lac[i] += v; l0 += leaky((float)a0[i] + xr[i] + v) * av[i];
      v = (float)b1[i]; lac[i] += v; l1 += leaky((float)a1[i] + xr[i] + v) * av[i];
      v = (float)b2[i]; lac[i] += v; l2 += leaky((float)a2[i] + xr[i] + v) * av[i];
      v = (float)b3[i]; lac[i] += v; l3 += leaky((float)a3[i] + xr[i] + v) * av[i];
    }
#pragma unroll
    for(int q = 8; q >= 1; q >>= 1){
      l0 += __shfl_xor(l0, q); l1 += __shfl_xor(l1, q);
      l2 += __shfl_xor(l2, q); l3 += __shfl_xor(l3, q);
    }
    float nm = fmaxf(m, fmaxf(fmaxf(l0, l1), fmaxf(l2, l3)));
    float sc = __expf(m - nm);
    float w0 = __expf(l0 - nm), w1 = __expf(l1 - nm);
    float w2 = __expf(l2 - nm), w3 = __expf(l3 - nm);
    den = den * sc + w0 + w1 + w2 + w3;
#pragma unroll
    for(int i = 0; i < 8; ++i)
      num[i] = num[i] * sc + w0 * (float)a0[i] + w1 * (float)a1[i]
                           + w2 * (float)a2[i] + w3 * (float)a3[i];
    m = nm;
  }
  for(; p < end; ++p){
    int s0 = srcs[p], r0 = rels[p];
    bf16x8 a0 = *(const bf16x8*)(xlb + (size_t)s0 * 1024 + o);
    bf16x8 b0 = *(const bf16x8*)(rpb + (size_t)r0 * 1024 + o);
    float l0 = 0.f;
#pragma unroll
    for(int i = 0; i < 8; ++i){
      float v = (float)b0[i]; lac[i] += v;
      l0 += leaky((float)a0[i] + xr[i] + v) * av[i];
    }
#pragma unroll
    for(int q = 8; q >= 1; q >>= 1) l0 += __shfl_xor(l0, q);
    float nm = fmaxf(m, l0);
    float sc = __expf(m - nm), w0 = __expf(l0 - nm);
    den = den * sc + w0;
#pragma unroll
    for(int i = 0; i < 8; ++i) num[i] = num[i] * sc + w0 * (float)a0[i];
    m = nm;
  }

  // self loop: edge_attr = mean of incoming rproj; self message = own xl row
  bf16x8 xlv = *(const bf16x8*)(xlb + (size_t)node * 1024 + o);
  float sl = 0.f;
#pragma unroll
  for(int i = 0; i < 8; ++i)
    sl += leaky((float)xlv[i] + xr[i] + lac[i] * inv) * av[i];
#pragma unroll
  for(int q = 8; q >= 1; q >>= 1) sl += __shfl_xor(sl, q);
  {
    float nm = fmaxf(m, sl);
    float sc = __expf(m - nm), w = __expf(sl - nm);
    den = den * sc + w;
#pragma unroll
    for(int i = 0; i < 8; ++i) num[i] = num[i] * sc + w * (float)xlv[i];
    m = nm;
  }

  // normalize + sum this wave's 4 heads (lane groups 0..3)
  f32x8 t;
  float d = 1.0f / den;
#pragma unroll
  for(int i = 0; i < 8; ++i) t[i] = num[i] * d;
#pragma unroll
  for(int i = 0; i < 8; ++i) t[i] += __shfl_xor(t[i], 16);
#pragma unroll
  for(int i = 0; i < 8; ++i) t[i] += __shfl_xor(t[i], 32);

  // combine the two halves via LDS
  if(half == 1 && lane < 16){
#pragma unroll
    for(int i = 0; i < 8; ++i) tsh[nib][lane * 8 + i] = t[i];
  }
  __syncthreads();
  if(active && half == 0 && lane < 16){
    const float* bp = bias + lane * 8;
    float* op = xout + (size_t)node * 128 + lane * 8;
    float q[8];
#pragma unroll
    for(int i = 0; i < 8; ++i) q[i] = (t[i] + tsh[nib][lane * 8 + i]) * 0.125f + bp[i];
    *(float4*)op       = make_float4(q[0], q[1], q[2], q[3]);
    *(float4*)(op + 4) = make_float4(q[4], q[5], q[6], q[7]);
  }
}

// ---------------- launch ----------------

extern "C" void kernel_launch(void* const* d_in, const int* in_sizes, int n_in,
                              void* d_out, int out_size, void* d_ws, size_t ws_size,
                              hipStream_t stream){
  const float* x0   = (const float*)d_in[0];
  const int*   ei   = (const int*)d_in[1];
  const float* rel0 = (const float*)d_in[2];
  const int*   ridx = (const int*)d_in[3];
  const float* Wl   = (const float*)d_in[4];
  const float* bl   = (const float*)d_in[5];
  const float* Wr   = (const float*)d_in[6];
  const float* br   = (const float*)d_in[7];
  const float* We   = (const float*)d_in[8];
  const float* att  = (const float*)d_in[9];
  const float* bias = (const float*)d_in[10];
  const float* Wb   = (const float*)d_in[11];
  const float* bb   = (const float*)d_in[12];

  const int D = 128, HC = 1024;
  const int N = in_sizes[0] / D;
  const int E = in_sizes[1] / 2;
  const int R = in_sizes[2] / D;
  const int WSZ = D * HC;

  const int* src = ei;
  const int* dst = ei + E;

  char* ws = (char*)d_ws;
  size_t off = 0;
  auto alloc = [&](size_t bytes) -> void* {
    void* p = ws + off;
    off += (bytes + 255) & ~(size_t)255;
    return p;
  };
  float*  rproj  = (float*)alloc((size_t)R * HC * 4);
  bf16_t* xlb    = (bf16_t*)alloc((size_t)N * HC * 2);
  bf16_t* xrb    = (bf16_t*)alloc((size_t)N * HC * 2);
  bf16_t* rpb    = (bf16_t*)alloc((size_t)R * HC * 2);
  float*  xbufA  = (float*)alloc((size_t)N * D * 4);
  float*  xbufB  = (float*)alloc((size_t)N * D * 4);
  float*  rbufA  = (float*)alloc((size_t)R * D * 4);
  float*  rbufB  = (float*)alloc((size_t)R * D * 4);
  // zeroed block: deg(N) + cursor(N) + cnt(256) + cur(256)
  int* zbase  = (int*)alloc((size_t)(2 * N + 512) * 4);
  int* deg    = zbase;
  int* cursor = zbase + N;
  int* cnt    = zbase + 2 * N;
  int* cur    = zbase + 2 * N + 256;
  const int ZCOUNT = 2 * N + 512;
  int* offs   = (int*)alloc((size_t)(N + 1) * 4);
  int* boff   = (int*)alloc(256 * 4);
  int* order  = (int*)alloc((size_t)N * 4);
  int* srcs   = (int*)alloc((size_t)E * 4);
  int* rels   = (int*)alloc((size_t)E * 4);
  bf16_t* tWl_h = (bf16_t*)alloc((size_t)N_LAYERS * WSZ * 2);
  bf16_t* tWl_l = (bf16_t*)alloc((size_t)N_LAYERS * WSZ * 2);
  bf16_t* tWr_h = (bf16_t*)alloc((size_t)N_LAYERS * WSZ * 2);
  bf16_t* tWr_l = (bf16_t*)alloc((size_t)N_LAYERS * WSZ * 2);
  bf16_t* tWe_h = (bf16_t*)alloc((size_t)N_LAYERS * WSZ * 2);
  bf16_t* tWe_l = (bf16_t*)alloc((size_t)N_LAYERS * WSZ * 2);
  bf16_t* tWb_h = (bf16_t*)alloc((size_t)N_LAYERS * WSZ * 2);
  bf16_t* tWb_l = (bf16_t*)alloc((size_t)N_LAYERS * WSZ * 2);
  float* xbuf[2] = {xbufA, xbufB};
  float* rbuf[2] = {rbufA, rbufB};

  float* out_x = (float*)d_out;
  float* out_r = (float*)d_out + (size_t)N * D;

  // CSR build + degree-descending order (once; edge structure is layer-invariant)
  fill_int_kernel<<<(ZCOUNT + 255) / 256, 256, 0, stream>>>(zbase, 0, ZCOUNT);
  hist_kernel<<<(E + 255) / 256, 256, 0, stream>>>(dst, E, deg);
  scan_kernel<<<1, 256, 0, stream>>>(deg, offs, N);
  scatter_kernel<<<(E + 255) / 256, 256, 0, stream>>>(src, dst, ridx, E, offs, cursor, srcs, rels);
  deg_hist_kernel<<<(N + 255) / 256, 256, 0, stream>>>(offs, N, cnt);
  deg_offset_kernel<<<1, 256, 0, stream>>>(cnt, boff);
  deg_scatter_kernel<<<(N + 255) / 256, 256, 0, stream>>>(offs, N, boff, cur, order);

  // weight prep: all 16 transpose+splits in ONE dispatch
  transpose_split_all_kernel<<<dim3(128, 1, 16), dim3(32, 8), 0, stream>>>(
      Wl, Wr, We, Wb, tWl_h, tWl_l, tWr_h, tWr_l, tWe_h, tWe_l, tWb_h, tWb_l);

  for(int l = 0; l < N_LAYERS; ++l){
    const float* xin = (l == 0) ? x0   : xbuf[(l + 1) & 1];
    float*       xo  = (l == N_LAYERS - 1) ? out_x : xbuf[l & 1];
    const float* rin = (l == 0) ? rel0 : rbuf[(l + 1) & 1];
    float*       ro  = (l == N_LAYERS - 1) ? out_r : rbuf[l & 1];
    size_t wo = (size_t)l * WSZ;
    const float* bl_l  = bl + (size_t)l * HC;
    const float* br_l  = br + (size_t)l * HC;
    const float* att_l = att + (size_t)l * 8 * 128;
    const float* bias_l= bias + (size_t)l * D;
    const float* bb_l  = bb + (size_t)l * D;

    // rproj = relations @ We (no bias) + bf16 copy
    gemm_mfma_kernel<false,false,true,false><<<dim3(HC/128, (R+127)/128), 256, 0, stream>>>(
        rin, tWe_h + wo, tWe_l + wo, nullptr, rproj, rpb, R, HC, D);
    // fused xl/xr projection, bf16 outputs only
    gemm_dual_mfma_kernel<<<dim3(HC/128, (N+127)/128), 256, 0, stream>>>(
        xin, tWl_h + wo, tWl_l + wo, tWr_h + wo, tWr_l + wo,
        bl_l, br_l, xlb, xrb, N, HC, D);
    // fused node pass: 2 waves per node, degree-sorted
    node_fused_kernel<<<(2 * N + 3) / 4, 256, 0, stream>>>(
        xlb, xrb, rpb, offs, srcs, rels, order, att_l, bias_l, xo, N);
    // relation update: ro = relu(rproj) @ Wb + bb, split-K over 8 slices
    fill_bias_kernel<<<(R * 128 + 255) / 256, 256, 0, stream>>>(ro, bb_l, R);
    gemm_mfma_kernel<true,false,false,true><<<dim3(D/128, (R+127)/128, 8), 256, 0, stream>>>(
        rproj, tWb_h + wo, tWb_l + wo, nullptr, ro, nullptr, R, D, HC);
  }
}

// Round 8
// 443.270 us; speedup vs baseline: 2.0968x; 1.2669x over previous
//
#include <hip/hip_runtime.h>
#include <hip/hip_bf16.h>
#include <math.h>

#define NEG_SLOPE 0.2f
#define N_LAYERS 4

typedef __bf16 bf16_t;
typedef __attribute__((ext_vector_type(8))) __bf16 bf16x8;
typedef __attribute__((ext_vector_type(4))) __bf16 bf16x4;
typedef __attribute__((ext_vector_type(4))) float f32x4;
typedef __attribute__((ext_vector_type(8))) float f32x8;

static __device__ __forceinline__ float leaky(float v){ return v > 0.f ? v : NEG_SLOPE * v; }

// ---------------- CSR build (edge structure fixed across layers) ----------------

__global__ void fill_int_kernel(int* __restrict__ p, int v, int n){
  int i = blockIdx.x*blockDim.x + threadIdx.x;
  if(i < n) p[i] = v;
}

__global__ void fill_bias_kernel(float* __restrict__ out, const float* __restrict__ b, int rows){
  int i = blockIdx.x*blockDim.x + threadIdx.x;
  if(i < rows * 128) out[i] = b[i & 127];
}

__global__ void hist_kernel(const int* __restrict__ dst, int E, int* __restrict__ deg){
  int e = blockIdx.x*blockDim.x + threadIdx.x;
  if(e < E) atomicAdd(&deg[dst[e]], 1);
}

// exclusive scan via wave shuffles: offs[0]=0, offs[i+1]=sum(deg[0..i]). One block, 256 thr.
__global__ void scan_kernel(const int* __restrict__ deg, int* __restrict__ offs, int N){
  __shared__ int wsum[4];
  int t = threadIdx.x, lane = t & 63, w = t >> 6;
  int carry = 0;
  for(int base = 0; base < N; base += 256){
    int v = (base + t < N) ? deg[base + t] : 0;
    int s = v;
#pragma unroll
    for(int o = 1; o < 64; o <<= 1){
      int u = __shfl_up(s, o);
      if(lane >= o) s += u;
    }
    if(lane == 63) wsum[w] = s;
    __syncthreads();
    int woff = 0;
    for(int i = 0; i < w; ++i) woff += wsum[i];
    if(base + t < N) offs[base + t + 1] = carry + woff + s;
    int tot = wsum[0] + wsum[1] + wsum[2] + wsum[3];
    __syncthreads();
    carry += tot;
  }
  if(t == 0) offs[0] = 0;
}

__global__ void scatter_kernel(const int* __restrict__ src, const int* __restrict__ dst,
                               const int* __restrict__ rel, int E,
                               const int* __restrict__ offs, int* __restrict__ cursor,
                               int* __restrict__ srcs, int* __restrict__ rels){
  int e = blockIdx.x*blockDim.x + threadIdx.x;
  if(e < E){
    int d = dst[e];
    int pos = offs[d] + atomicAdd(&cursor[d], 1);
    srcs[pos] = src[e];
    rels[pos] = rel[e];
  }
}

// ---- degree-descending counting sort, LDS-privatized (no global atomic hotspots) ----

__global__ void deg_bhist_kernel(const int* __restrict__ offs, int N, int* __restrict__ blkhist){
  __shared__ int h[256];
  int t = threadIdx.x;
  h[t] = 0; __syncthreads();
  int i = blockIdx.x * 256 + t;
  if(i < N){
    int d = offs[i+1] - offs[i]; if(d > 255) d = 255;
    atomicAdd(&h[d], 1);          // LDS atomic: cheap
  }
  __syncthreads();
  blkhist[blockIdx.x * 256 + t] = h[t];
}

// single block: column-scan blkhist per degree, then add descending-degree bucket starts
__global__ void deg_base_kernel(int* __restrict__ blkhist, int nb){
  __shared__ int tot[256];
  int d = threadIdx.x;
  int s = 0;
  for(int b = 0; b < nb; ++b){
    int v = blkhist[b * 256 + d];
    blkhist[b * 256 + d] = s;
    s += v;
  }
  tot[d] = s; __syncthreads();
  int start = 0;
  for(int k = d + 1; k < 256; ++k) start += tot[k];
  for(int b = 0; b < nb; ++b) blkhist[b * 256 + d] += start;
}

__global__ void deg_place_kernel(const int* __restrict__ offs, int N,
                                 const int* __restrict__ blkhist, int* __restrict__ order){
  __shared__ int cur[256];
  int t = threadIdx.x;
  cur[t] = blkhist[blockIdx.x * 256 + t];
  __syncthreads();
  int i = blockIdx.x * 256 + t;
  if(i < N){
    int d = offs[i+1] - offs[i]; if(d > 255) d = 255;
    int pos = atomicAdd(&cur[d], 1);   // LDS atomic
    order[pos] = i;
  }
}

// ---------------- batched weight transpose + bf16 hi/lo split (one dispatch) ----

__global__ void transpose_split_all_kernel(
    const float* __restrict__ Wl, const float* __restrict__ Wr,
    const float* __restrict__ We, const float* __restrict__ Wb,
    bf16_t* __restrict__ tWlh, bf16_t* __restrict__ tWll,
    bf16_t* __restrict__ tWrh, bf16_t* __restrict__ tWrl,
    bf16_t* __restrict__ tWeh, bf16_t* __restrict__ tWel,
    bf16_t* __restrict__ tWbh, bf16_t* __restrict__ tWbl){
  __shared__ float t[32][33];
  const int z = blockIdx.z, type = z >> 2, layer = z & 3;
  const int K  = (type < 3) ? 128 : 1024;
  const int Nn = (type < 3) ? 1024 : 128;
  const float* W; bf16_t* Th; bf16_t* Tl;
  if(type == 0){ W = Wl; Th = tWlh; Tl = tWll; }
  else if(type == 1){ W = Wr; Th = tWrh; Tl = tWrl; }
  else if(type == 2){ W = We; Th = tWeh; Tl = tWel; }
  else { W = Wb; Th = tWbh; Tl = tWbl; }
  size_t wo = (size_t)layer * 131072;
  W += wo; Th += wo; Tl += wo;
  const int nbx = K / 32;
  const int bx = blockIdx.x % nbx, by = blockIdx.x / nbx;
  const int k0 = bx * 32, n0 = by * 32;
  const int tx = threadIdx.x, ty = threadIdx.y;
#pragma unroll
  for(int i = 0; i < 4; ++i)
    t[ty*4 + i][tx] = W[(size_t)(k0 + ty*4 + i) * Nn + n0 + tx];
  __syncthreads();
#pragma unroll
  for(int i = 0; i < 4; ++i){
    int n = ty*4 + i;
    float v = t[tx][n];
    bf16_t h = (bf16_t)v;
    bf16_t l = (bf16_t)(v - (float)h);
    Th[(size_t)(n0 + n) * K + k0 + tx] = h;
    Tl[(size_t)(n0 + n) * K + k0 + tx] = l;
  }
}

// ---------------- MFMA split-bf16 GEMM (split-K relation update) ----------------

template<bool RELU_A, bool HAS_BIAS, bool WRITE_BF16, bool SPLITK>
__global__ __launch_bounds__(256) void gemm_mfma_kernel(
    const float* __restrict__ A,
    const bf16_t* __restrict__ Bt_hi, const bf16_t* __restrict__ Bt_lo,
    const float* __restrict__ bias, float* __restrict__ C, bf16_t* __restrict__ Cb,
    int M, int N, int K){
  constexpr int LDK = 40;
  __shared__ bf16_t Ah[128 * LDK];
  __shared__ bf16_t Al[128 * LDK];
  __shared__ bf16_t Bh[128 * LDK];
  __shared__ bf16_t Bl[128 * LDK];

  const int tid  = threadIdx.x;
  const int lane = tid & 63;
  const int wid  = tid >> 6;
  const int wm = wid >> 1, wn = wid & 1;
  const int row0 = blockIdx.y * 128, col0 = blockIdx.x * 128;
  const int l15 = lane & 15;
  const int kb  = (lane >> 4) * 8;

  f32x4 acc[4][4];
#pragma unroll
  for(int m = 0; m < 4; ++m)
#pragma unroll
    for(int n = 0; n < 4; ++n) acc[m][n] = (f32x4){0.f, 0.f, 0.f, 0.f};

  int kbeg = 0, kend = K;
  if(SPLITK){ kbeg = blockIdx.z * 128; kend = kbeg + 128; }

  for(int k0 = kbeg; k0 < kend; k0 += 32){
    __syncthreads();
#pragma unroll
    for(int i = 0; i < 4; ++i){
      int f = tid + i * 256;
      int r = f >> 3, kq = f & 7;
      float4 v = make_float4(0.f, 0.f, 0.f, 0.f);
      if(row0 + r < M) v = *(const float4*)(A + (size_t)(row0 + r) * K + k0 + kq * 4);
      if(RELU_A){ v.x = fmaxf(v.x, 0.f); v.y = fmaxf(v.y, 0.f); v.z = fmaxf(v.z, 0.f); v.w = fmaxf(v.w, 0.f); }
      bf16_t h0 = (bf16_t)v.x, h1 = (bf16_t)v.y, h2 = (bf16_t)v.z, h3 = (bf16_t)v.w;
      bf16x4 hv = (bf16x4){h0, h1, h2, h3};
      bf16x4 lv = (bf16x4){(bf16_t)(v.x - (float)h0), (bf16_t)(v.y - (float)h1),
                           (bf16_t)(v.z - (float)h2), (bf16_t)(v.w - (float)h3)};
      *(bf16x4*)&Ah[r * LDK + kq * 4] = hv;
      *(bf16x4*)&Al[r * LDK + kq * 4] = lv;
    }
#pragma unroll
    for(int i = 0; i < 2; ++i){
      int f = tid + i * 256;
      int n = f >> 2, kq = f & 3;
      *(bf16x8*)&Bh[n * LDK + kq * 8] = *(const bf16x8*)(Bt_hi + (size_t)(col0 + n) * K + k0 + kq * 8);
      *(bf16x8*)&Bl[n * LDK + kq * 8] = *(const bf16x8*)(Bt_lo + (size_t)(col0 + n) * K + k0 + kq * 8);
    }
    __syncthreads();

    bf16x8 ah[4], al[4], bh[4], bl[4];
#pragma unroll
    for(int m = 0; m < 4; ++m){
      int r = wm * 64 + m * 16 + l15;
      ah[m] = *(bf16x8*)&Ah[r * LDK + kb];
      al[m] = *(bf16x8*)&Al[r * LDK + kb];
    }
#pragma unroll
    for(int n = 0; n < 4; ++n){
      int c = wn * 64 + n * 16 + l15;
      bh[n] = *(bf16x8*)&Bh[c * LDK + kb];
      bl[n] = *(bf16x8*)&Bl[c * LDK + kb];
    }
#pragma unroll
    for(int m = 0; m < 4; ++m)
#pragma unroll
      for(int n = 0; n < 4; ++n){
        acc[m][n] = __builtin_amdgcn_mfma_f32_16x16x32_bf16(ah[m], bh[n], acc[m][n], 0, 0, 0);
        acc[m][n] = __builtin_amdgcn_mfma_f32_16x16x32_bf16(ah[m], bl[n], acc[m][n], 0, 0, 0);
        acc[m][n] = __builtin_amdgcn_mfma_f32_16x16x32_bf16(al[m], bh[n], acc[m][n], 0, 0, 0);
      }
  }

  // D layout: row = (lane>>4)*4 + reg, col = lane&15
#pragma unroll
  for(int n = 0; n < 4; ++n){
    int col = col0 + wn * 64 + n * 16 + l15;
    float bv = HAS_BIAS ? bias[col] : 0.f;
#pragma unroll
    for(int m = 0; m < 4; ++m){
      int rbase = row0 + wm * 64 + m * 16 + (lane >> 4) * 4;
#pragma unroll
      for(int r = 0; r < 4; ++r){
        if(rbase + r < M){
          size_t idx = (size_t)(rbase + r) * N + col;
          if(SPLITK){
            atomicAdd(&C[idx], acc[m][n][r]);
          } else {
            float val = acc[m][n][r] + bv;
            C[idx] = val;
            if(WRITE_BF16) Cb[idx] = (bf16_t)val;
          }
        }
      }
    }
  }
}

// ---------------- merged projection GEMM: rproj + xl + xr in ONE dispatch ----------------
// Uniform 128x128 single-output jobs, K=128, 40KB LDS -> 3 blocks/CU.
// job 0 (rjobs blocks):  rproj = rin @ We^T      -> fp32 rproj + bf16 rpb
// job 1 (xjobs blocks):  xlb   = xin @ Wl^T + bl -> bf16 (LDS-repacked stores)
// job 2 (xjobs blocks):  xrb   = xin @ Wr^T + br -> bf16

__global__ __launch_bounds__(256, 3) void gemm_proj_kernel(
    const float* __restrict__ Ar, const float* __restrict__ Ax,
    const bf16_t* __restrict__ Weh, const bf16_t* __restrict__ Wel,
    const bf16_t* __restrict__ Wlh, const bf16_t* __restrict__ Wll,
    const bf16_t* __restrict__ Wrh, const bf16_t* __restrict__ Wrl,
    const float* __restrict__ biasL, const float* __restrict__ biasR,
    float* __restrict__ rproj, bf16_t* __restrict__ rpb,
    bf16_t* __restrict__ xlb, bf16_t* __restrict__ xrb,
    int R, int Nn, int rjobs, int xjobs){
  constexpr int LDK = 40;
  __shared__ char smem[40960];
  bf16_t* Ah = (bf16_t*)smem;
  bf16_t* Al = (bf16_t*)(smem + 10240);
  bf16_t* Bh = (bf16_t*)(smem + 20480);
  bf16_t* Bl = (bf16_t*)(smem + 30720);

  const int tid  = threadIdx.x;
  const int lane = tid & 63;
  const int wid  = tid >> 6;
  const int wm = wid >> 1, wn = wid & 1;
  const int l15 = lane & 15;
  const int kb  = (lane >> 4) * 8;

  // XCD-bijective swizzle over the whole merged grid
  int nwg = gridDim.x;
  int lin = blockIdx.x;
  int w = ((nwg & 7) == 0) ? ((lin & 7) * (nwg >> 3) + (lin >> 3)) : lin;
  int job, jw;
  if(w < rjobs){ job = 0; jw = w; }
  else if(w < rjobs + xjobs){ job = 1; jw = w - rjobs; }
  else { job = 2; jw = w - rjobs - xjobs; }

  const float*  A   = (job == 0) ? Ar : Ax;
  const bf16_t* Bth = (job == 0) ? Weh : (job == 1) ? Wlh : Wrh;
  const bf16_t* Btl = (job == 0) ? Wel : (job == 1) ? Wll : Wrl;
  const int M = (job == 0) ? R : Nn;
  const int row0 = (jw >> 3) * 128, col0 = (jw & 7) * 128;

  f32x4 acc[4][4];
#pragma unroll
  for(int m = 0; m < 4; ++m)
#pragma unroll
    for(int n = 0; n < 4; ++n) acc[m][n] = (f32x4){0.f, 0.f, 0.f, 0.f};

  for(int k0 = 0; k0 < 128; k0 += 32){
    __syncthreads();
#pragma unroll
    for(int i = 0; i < 4; ++i){
      int f = tid + i * 256;
      int r = f >> 3, kq = f & 7;
      float4 v = make_float4(0.f, 0.f, 0.f, 0.f);
      if(row0 + r < M) v = *(const float4*)(A + (size_t)(row0 + r) * 128 + k0 + kq * 4);
      bf16_t h0 = (bf16_t)v.x, h1 = (bf16_t)v.y, h2 = (bf16_t)v.z, h3 = (bf16_t)v.w;
      bf16x4 hv = (bf16x4){h0, h1, h2, h3};
      bf16x4 lv = (bf16x4){(bf16_t)(v.x - (float)h0), (bf16_t)(v.y - (float)h1),
                           (bf16_t)(v.z - (float)h2), (bf16_t)(v.w - (float)h3)};
      *(bf16x4*)&Ah[r * LDK + kq * 4] = hv;
      *(bf16x4*)&Al[r * LDK + kq * 4] = lv;
    }
#pragma unroll
    for(int i = 0; i < 2; ++i){
      int f = tid + i * 256;
      int n = f >> 2, kq = f & 3;
      size_t g = (size_t)(col0 + n) * 128 + k0 + kq * 8;
      *(bf16x8*)&Bh[n * LDK + kq * 8] = *(const bf16x8*)(Bth + g);
      *(bf16x8*)&Bl[n * LDK + kq * 8] = *(const bf16x8*)(Btl + g);
    }
    __syncthreads();

    bf16x8 ah[4], al[4], bh[4], bl[4];
#pragma unroll
    for(int m = 0; m < 4; ++m){
      int r = wm * 64 + m * 16 + l15;
      ah[m] = *(bf16x8*)&Ah[r * LDK + kb];
      al[m] = *(bf16x8*)&Al[r * LDK + kb];
    }
#pragma unroll
    for(int n = 0; n < 4; ++n){
      int c = wn * 64 + n * 16 + l15;
      bh[n] = *(bf16x8*)&Bh[c * LDK + kb];
      bl[n] = *(bf16x8*)&Bl[c * LDK + kb];
    }
#pragma unroll
    for(int m = 0; m < 4; ++m)
#pragma unroll
      for(int n = 0; n < 4; ++n){
        acc[m][n] = __builtin_amdgcn_mfma_f32_16x16x32_bf16(ah[m], bh[n], acc[m][n], 0, 0, 0);
        acc[m][n] = __builtin_amdgcn_mfma_f32_16x16x32_bf16(ah[m], bl[n], acc[m][n], 0, 0, 0);
        acc[m][n] = __builtin_amdgcn_mfma_f32_16x16x32_bf16(al[m], bh[n], acc[m][n], 0, 0, 0);
      }
  }

  if(job == 0){
    // rproj: direct fp32 + bf16 stores (no bias)
#pragma unroll
    for(int n = 0; n < 4; ++n){
      int col = col0 + wn * 64 + n * 16 + l15;
#pragma unroll
      for(int m = 0; m < 4; ++m){
        int rbase = row0 + wm * 64 + m * 16 + (lane >> 4) * 4;
#pragma unroll
        for(int r = 0; r < 4; ++r){
          if(rbase + r < M){
            size_t idx = (size_t)(rbase + r) * 1024 + col;
            float val = acc[m][n][r];
            rproj[idx] = val;
            rpb[idx]   = (bf16_t)val;
          }
        }
      }
    }
  } else {
    // xl / xr: bias + bf16 via padded LDS repack (conflict-free), coalesced 16B stores
    const float* bias = (job == 1) ? biasL : biasR;
    bf16_t* dst = (job == 1) ? xlb : xrb;
    bf16_t* tile = (bf16_t*)smem;   // 128 x 132 bf16 = 33792 B
    __syncthreads();
#pragma unroll
    for(int n = 0; n < 4; ++n){
      int col = wn * 64 + n * 16 + l15;
      float bv = bias[col0 + col];
#pragma unroll
      for(int m = 0; m < 4; ++m){
        int rb = wm * 64 + m * 16 + (lane >> 4) * 4;
#pragma unroll
        for(int r = 0; r < 4; ++r)
          tile[(rb + r) * 132 + col] = (bf16_t)(acc[m][n][r] + bv);
      }
    }
    __syncthreads();
#pragma unroll
    for(int i = 0; i < 8; ++i){
      int ei = i * 2048 + tid * 8;
      int rr = ei >> 7, cc = ei & 127;
      if(row0 + rr < M)
        *(bf16x8*)(dst + (size_t)(row0 + rr) * 1024 + col0 + cc) = *(bf16x8*)&tile[rr * 132 + cc];
    }
  }
}

// ---------------- fused node kernel: TWO waves per node (one per 4-head half) ----------

__global__ __launch_bounds__(256) void node_fused_kernel(
    const bf16_t* __restrict__ xlb, const bf16_t* __restrict__ xrb,
    const bf16_t* __restrict__ rpb,
    const int* __restrict__ offs, const int* __restrict__ srcs, const int* __restrict__ rels,
    const int* __restrict__ order,
    const float* __restrict__ att, const float* __restrict__ bias,
    float* __restrict__ xout, int N){
  __shared__ float tsh[2][128];
  const int wid  = threadIdx.x >> 6;
  const int lane = threadIdx.x & 63;
  const int nib  = wid >> 1;
  const int half = wid & 1;
  const int slot = blockIdx.x * 2 + nib;
  const bool active = slot < N;
  const int node = active ? order[slot] : 0;
  int beg = 0, end = 0;
  if(active){ beg = offs[node]; end = offs[node + 1]; }
  const float inv = 1.0f / fmaxf((float)(end - beg), 1.0f);

  const int o  = (half * 64 + lane) * 8;
  const int c0 = (lane & 15) * 8;
  const int h  = half * 4 + (lane >> 4);
  f32x8 av = *(const f32x8*)(att + h * 128 + c0);
  bf16x8 xrv = *(const bf16x8*)(xrb + (size_t)node * 1024 + o);
  f32x8 xr;
#pragma unroll
  for(int i = 0; i < 8; ++i) xr[i] = (float)xrv[i];

  f32x8 lac, num;
#pragma unroll
  for(int i = 0; i < 8; ++i){ lac[i] = 0.f; num[i] = 0.f; }
  float m = -INFINITY, den = 0.f;

  int p = beg;
  for(; p + 3 < end; p += 4){
    int s0 = srcs[p],   r0 = rels[p];
    int s1 = srcs[p+1], r1 = rels[p+1];
    int s2 = srcs[p+2], r2 = rels[p+2];
    int s3 = srcs[p+3], r3 = rels[p+3];
    bf16x8 a0 = *(const bf16x8*)(xlb + (size_t)s0 * 1024 + o);
    bf16x8 b0 = *(const bf16x8*)(rpb + (size_t)r0 * 1024 + o);
    bf16x8 a1 = *(const bf16x8*)(xlb + (size_t)s1 * 1024 + o);
    bf16x8 b1 = *(const bf16x8*)(rpb + (size_t)r1 * 1024 + o);
    bf16x8 a2 = *(const bf16x8*)(xlb + (size_t)s2 * 1024 + o);
    bf16x8 b2 = *(const bf16x8*)(rpb + (size_t)r2 * 1024 + o);
    bf16x8 a3 = *(const bf16x8*)(xlb + (size_t)s3 * 1024 + o);
    bf16x8 b3 = *(const bf16x8*)(rpb + (size_t)r3 * 1024 + o);
    float l0 = 0.f, l1 = 0.f, l2 = 0.f, l3 = 0.f;
#pragma unroll
    for(int i = 0; i < 8; ++i){
      float v;
      v = (float)b0[i]; lac[i] += v; l0 += leaky((float)a0[i] + xr[i] + v) * av[i];
      v = (float)b1[i]; lac[i] += v; l1 += leaky((float)a1[i] + xr[i] + v) * av[i];
      v = (float)b2[i]; lac[i] += v; l2 += leaky((float)a2[i] + xr[i] + v) * av[i];
      v = (float)b3[i]; lac[i] += v; l3 += leaky((float)a3[i] + xr[i] + v) * av[i];
    }
#pragma unroll
    for(int q = 8; q >= 1; q >>= 1){
      l0 += __shfl_xor(l0, q); l1 += __shfl_xor(l1, q);
      l2 += __shfl_xor(l2, q); l3 += __shfl_xor(l3, q);
    }
    float nm = fmaxf(m, fmaxf(fmaxf(l0, l1), fmaxf(l2, l3)));
    float sc = __expf(m - nm);
    float w0 = __expf(l0 - nm), w1 = __expf(l1 - nm);
    float w2 = __expf(l2 - nm), w3 = __expf(l3 - nm);
    den = den * sc + w0 + w1 + w2 + w3;
#pragma unroll
    for(int i = 0; i < 8; ++i)
      num[i] = num[i] * sc + w0 * (float)a0[i] + w1 * (float)a1[i]
                           + w2 * (float)a2[i] + w3 * (float)a3[i];
    m = nm;
  }
  for(; p < end; ++p){
    int s0 = srcs[p], r0 = rels[p];
    bf16x8 a0 = *(const bf16x8*)(xlb + (size_t)s0 * 1024 + o);
    bf16x8 b0 = *(const bf16x8*)(rpb + (size_t)r0 * 1024 + o);
    float l0 = 0.f;
#pragma unroll
    for(int i = 0; i < 8; ++i){
      float v = (float)b0[i]; lac[i] += v;
      l0 += leaky((float)a0[i] + xr[i] + v) * av[i];
    }
#pragma unroll
    for(int q = 8; q >= 1; q >>= 1) l0 += __shfl_xor(l0, q);
    float nm = fmaxf(m, l0);
    float sc = __expf(m - nm), w0 = __expf(l0 - nm);
    den = den * sc + w0;
#pragma unroll
    for(int i = 0; i < 8; ++i) num[i] = num[i] * sc + w0 * (float)a0[i];
    m = nm;
  }

  // self loop: edge_attr = mean of incoming rproj; self message = own xl row
  bf16x8 xlv = *(const bf16x8*)(xlb + (size_t)node * 1024 + o);
  float sl = 0.f;
#pragma unroll
  for(int i = 0; i < 8; ++i)
    sl += leaky((float)xlv[i] + xr[i] + lac[i] * inv) * av[i];
#pragma unroll
  for(int q = 8; q >= 1; q >>= 1) sl += __shfl_xor(sl, q);
  {
    float nm = fmaxf(m, sl);
    float sc = __expf(m - nm), w = __expf(sl - nm);
    den = den * sc + w;
#pragma unroll
    for(int i = 0; i < 8; ++i) num[i] = num[i] * sc + w * (float)xlv[i];
    m = nm;
  }

  f32x8 t;
  float d = 1.0f / den;
#pragma unroll
  for(int i = 0; i < 8; ++i) t[i] = num[i] * d;
#pragma unroll
  for(int i = 0; i < 8; ++i) t[i] += __shfl_xor(t[i], 16);
#pragma unroll
  for(int i = 0; i < 8; ++i) t[i] += __shfl_xor(t[i], 32);

  if(half == 1 && lane < 16){
#pragma unroll
    for(int i = 0; i < 8; ++i) tsh[nib][lane * 8 + i] = t[i];
  }
  __syncthreads();
  if(active && half == 0 && lane < 16){
    const float* bp = bias + lane * 8;
    float* op = xout + (size_t)node * 128 + lane * 8;
    float q[8];
#pragma unroll
    for(int i = 0; i < 8; ++i) q[i] = (t[i] + tsh[nib][lane * 8 + i]) * 0.125f + bp[i];
    *(float4*)op       = make_float4(q[0], q[1], q[2], q[3]);
    *(float4*)(op + 4) = make_float4(q[4], q[5], q[6], q[7]);
  }
}

// ---------------- launch ----------------

extern "C" void kernel_launch(void* const* d_in, const int* in_sizes, int n_in,
                              void* d_out, int out_size, void* d_ws, size_t ws_size,
                              hipStream_t stream){
  const float* x0   = (const float*)d_in[0];
  const int*   ei   = (const int*)d_in[1];
  const float* rel0 = (const float*)d_in[2];
  const int*   ridx = (const int*)d_in[3];
  const float* Wl   = (const float*)d_in[4];
  const float* bl   = (const float*)d_in[5];
  const float* Wr   = (const float*)d_in[6];
  const float* br   = (const float*)d_in[7];
  const float* We   = (const float*)d_in[8];
  const float* att  = (const float*)d_in[9];
  const float* bias = (const float*)d_in[10];
  const float* Wb   = (const float*)d_in[11];
  const float* bb   = (const float*)d_in[12];

  const int D = 128, HC = 1024;
  const int N = in_sizes[0] / D;
  const int E = in_sizes[1] / 2;
  const int R = in_sizes[2] / D;
  const int WSZ = D * HC;
  const int NB = (N + 255) / 256;

  const int* src = ei;
  const int* dst = ei + E;

  char* ws = (char*)d_ws;
  size_t off = 0;
  auto alloc = [&](size_t bytes) -> void* {
    void* p = ws + off;
    off += (bytes + 255) & ~(size_t)255;
    return p;
  };
  float*  rproj  = (float*)alloc((size_t)R * HC * 4);
  bf16_t* xlb    = (bf16_t*)alloc((size_t)N * HC * 2);
  bf16_t* xrb    = (bf16_t*)alloc((size_t)N * HC * 2);
  bf16_t* rpb    = (bf16_t*)alloc((size_t)R * HC * 2);
  float*  xbufA  = (float*)alloc((size_t)N * D * 4);
  float*  xbufB  = (float*)alloc((size_t)N * D * 4);
  float*  rbufA  = (float*)alloc((size_t)R * D * 4);
  float*  rbufB  = (float*)alloc((size_t)R * D * 4);
  int* zbase   = (int*)alloc((size_t)(2 * N) * 4);   // deg + cursor (zeroed)
  int* deg     = zbase;
  int* cursor  = zbase + N;
  int* offs    = (int*)alloc((size_t)(N + 1) * 4);
  int* blkhist = (int*)alloc((size_t)NB * 256 * 4);
  int* order   = (int*)alloc((size_t)N * 4);
  int* srcs    = (int*)alloc((size_t)E * 4);
  int* rels    = (int*)alloc((size_t)E * 4);
  bf16_t* tWl_h = (bf16_t*)alloc((size_t)N_LAYERS * WSZ * 2);
  bf16_t* tWl_l = (bf16_t*)alloc((size_t)N_LAYERS * WSZ * 2);
  bf16_t* tWr_h = (bf16_t*)alloc((size_t)N_LAYERS * WSZ * 2);
  bf16_t* tWr_l = (bf16_t*)alloc((size_t)N_LAYERS * WSZ * 2);
  bf16_t* tWe_h = (bf16_t*)alloc((size_t)N_LAYERS * WSZ * 2);
  bf16_t* tWe_l = (bf16_t*)alloc((size_t)N_LAYERS * WSZ * 2);
  bf16_t* tWb_h = (bf16_t*)alloc((size_t)N_LAYERS * WSZ * 2);
  bf16_t* tWb_l = (bf16_t*)alloc((size_t)N_LAYERS * WSZ * 2);
  float* xbuf[2] = {xbufA, xbufB};
  float* rbuf[2] = {rbufA, rbufB};

  float* out_x = (float*)d_out;
  float* out_r = (float*)d_out + (size_t)N * D;

  // CSR build + degree-descending order (LDS-privatized sort; no hot global atomics)
  fill_int_kernel<<<(2 * N + 255) / 256, 256, 0, stream>>>(zbase, 0, 2 * N);
  hist_kernel<<<(E + 255) / 256, 256, 0, stream>>>(dst, E, deg);
  scan_kernel<<<1, 256, 0, stream>>>(deg, offs, N);
  scatter_kernel<<<(E + 255) / 256, 256, 0, stream>>>(src, dst, ridx, E, offs, cursor, srcs, rels);
  deg_bhist_kernel<<<NB, 256, 0, stream>>>(offs, N, blkhist);
  deg_base_kernel<<<1, 256, 0, stream>>>(blkhist, NB);
  deg_place_kernel<<<NB, 256, 0, stream>>>(offs, N, blkhist, order);

  // weight prep: all 16 transpose+splits in ONE dispatch
  transpose_split_all_kernel<<<dim3(128, 1, 16), dim3(32, 8), 0, stream>>>(
      Wl, Wr, We, Wb, tWl_h, tWl_l, tWr_h, tWr_l, tWe_h, tWe_l, tWb_h, tWb_l);

  const int rjobs = ((R + 127) / 128) * (HC / 128);
  const int xjobs = ((N + 127) / 128) * (HC / 128);

  for(int l = 0; l < N_LAYERS; ++l){
    const float* xin = (l == 0) ? x0   : xbuf[(l + 1) & 1];
    float*       xo  = (l == N_LAYERS - 1) ? out_x : xbuf[l & 1];
    const float* rin = (l == 0) ? rel0 : rbuf[(l + 1) & 1];
    float*       ro  = (l == N_LAYERS - 1) ? out_r : rbuf[l & 1];
    size_t wo = (size_t)l * WSZ;
    const float* bl_l  = bl + (size_t)l * HC;
    const float* br_l  = br + (size_t)l * HC;
    const float* att_l = att + (size_t)l * 8 * 128;
    const float* bias_l= bias + (size_t)l * D;
    const float* bb_l  = bb + (size_t)l * D;

    // merged projections: rproj(+rpb), xlb, xrb — one dispatch
    gemm_proj_kernel<<<rjobs + 2 * xjobs, 256, 0, stream>>>(
        rin, xin, tWe_h + wo, tWe_l + wo, tWl_h + wo, tWl_l + wo, tWr_h + wo, tWr_l + wo,
        bl_l, br_l, rproj, rpb, xlb, xrb, R, N, rjobs, xjobs);
    // fused node pass: 2 waves per node, degree-sorted
    node_fused_kernel<<<(2 * N + 3) / 4, 256, 0, stream>>>(
        xlb, xrb, rpb, offs, srcs, rels, order, att_l, bias_l, xo, N);
    // relation update: ro = relu(rproj) @ Wb + bb, split-K over 8 slices
    fill_bias_kernel<<<(R * 128 + 255) / 256, 256, 0, stream>>>(ro, bb_l, R);
    gemm_mfma_kernel<true,false,false,true><<<dim3(D/128, (R+127)/128, 8), 256, 0, stream>>>(
        rproj, tWb_h + wo, tWb_l + wo, nullptr, ro, nullptr, R, D, HC);
  }
}